// Round 5
// baseline (185.672 us; speedup 1.0000x reference)
//
#include <hip/hip_runtime.h>
#include <hip/hip_fp16.h>
#include <math.h>

#define T_LEN 8192
#define CHN 128
#define BATCH 16
#define NKCHUNK 16   // k-chunk = 512; grid = 16x16 = 256 blocks
#define KSTAGE 128   // R13: k elems staged per LDS tile (was 64) -> half the barriers
#define NITER (T_LEN / NKCHUNK / KSTAGE)   // = 4 stage iterations per block

typedef short bf16x8 __attribute__((ext_vector_type(8)));
typedef float f32x16 __attribute__((ext_vector_type(16)));

#define SIN8 0.3826834323650898f
#define COS8 0.9238795325112868f
#define SROW 136         // LDS row stride (ushorts) = 272 B; dword stride 68 = 4 mod 32 (2-way, free)
#define SPLANE (128 * SROW)

__device__ __forceinline__ ushort f2bf(float f) {
    unsigned u = __float_as_uint(f);
    unsigned r = (u + 0x7fffu + ((u >> 16) & 1u)) >> 16;
    return (ushort)r;
}

// Barrier that drains ONLY LDS ops (lgkmcnt), leaving global prefetch loads
// in flight. __syncthreads() emits s_waitcnt vmcnt(0) before s_barrier, which
// would drain the depth-2 prefetch every iteration.
__device__ __forceinline__ void barrier_lds_only() {
    asm volatile("s_waitcnt lgkmcnt(0)" ::: "memory");
    __builtin_amdgcn_s_barrier();
}

__device__ __forceinline__ float2 cadd(float2 a, float2 b) { return make_float2(a.x + b.x, a.y + b.y); }
__device__ __forceinline__ float2 csub(float2 a, float2 b) { return make_float2(a.x - b.x, a.y - b.y); }
__device__ __forceinline__ float2 cmul(float2 a, float2 b) {
    return make_float2(a.x * b.x - a.y * b.y, a.x * b.y + a.y * b.x);
}

__device__ __forceinline__ void r4f(float2 x0, float2 x1, float2 x2, float2 x3,
                                    float2 wa, float2 wb, float2 wc,
                                    float2& y0, float2& y1, float2& y2, float2& y3) {
    float2 t0 = cadd(x0, x2), t1 = csub(x0, x2);
    float2 t2 = cadd(x1, x3), t3 = csub(x1, x3);
    y0 = cadd(t0, t2);
    y1 = cmul(csub(t0, t2), wb);
    y2 = cmul(make_float2(t1.x + t3.y, t1.y - t3.x), wa);
    y3 = cmul(make_float2(t1.x - t3.y, t1.y + t3.x), wc);
}

__device__ __forceinline__ void r4i(float2 x0, float2 x1, float2 x2, float2 x3,
                                    float2 wa, float2 wb, float2 wc,
                                    float2& y0, float2& y1, float2& y2, float2& y3) {
    float2 a1 = cmul(x1, wb);
    float2 a2 = cmul(x2, wa);
    float2 a3 = cmul(x3, wc);
    float2 u0 = cadd(x0, a1), u1 = csub(x0, a1);
    float2 p = cadd(a2, a3);
    float2 m = make_float2(-(a2.y - a3.y), a2.x - a3.x);
    y0 = cadd(u0, p); y2 = csub(u0, p);
    y1 = cadd(u1, m); y3 = csub(u1, m);
}

__device__ __forceinline__ void r8f(const float2* x, float sn, float cs, float2* y) {
    const float r22 = 0.70710678118654752f;
    float2 w1 = make_float2(cs, sn);
    float2 w2 = make_float2(cs * cs - sn * sn, 2.f * cs * sn);
    float2 w4 = cmul(w2, w2);
    float2 w6 = cmul(w4, w2);
    float2 u0 = cadd(x[0], x[4]), u1 = cadd(x[1], x[5]), u2 = cadd(x[2], x[6]), u3 = cadd(x[3], x[7]);
    float2 e0 = cmul(csub(x[0], x[4]), w1);
    float2 e1 = cmul(csub(x[1], x[5]), w1);
    float2 e2 = cmul(csub(x[2], x[6]), w1);
    float2 e3 = cmul(csub(x[3], x[7]), w1);
    float2 v0 = e0;
    float2 v1 = make_float2(r22 * (e1.x + e1.y), r22 * (e1.y - e1.x));
    float2 v2 = make_float2(e2.y, -e2.x);
    float2 v3 = make_float2(r22 * (e3.y - e3.x), -r22 * (e3.x + e3.y));
    r4f(u0, u1, u2, u3, w2, w4, w6, y[0], y[1], y[2], y[3]);
    r4f(v0, v1, v2, v3, w2, w4, w6, y[4], y[5], y[6], y[7]);
}

__device__ __forceinline__ void r8i(const float2* x, float sn, float cs, float2* y) {
    const float r22 = 0.70710678118654752f;
    float2 w1 = make_float2(cs, sn);
    float2 w2 = make_float2(cs * cs - sn * sn, 2.f * cs * sn);
    float2 w4 = cmul(w2, w2);
    float2 w6 = cmul(w4, w2);
    float2 g0, g1, g2, g3, g4, g5, g6, g7;
    r4i(x[0], x[1], x[2], x[3], w2, w4, w6, g0, g1, g2, g3);
    r4i(x[4], x[5], x[6], x[7], w2, w4, w6, g4, g5, g6, g7);
    float2 t0 = cmul(g4, w1);
    float2 e1 = cmul(g5, w1);
    float2 e2 = cmul(g6, w1);
    float2 e3 = cmul(g7, w1);
    float2 t1 = make_float2(r22 * (e1.x - e1.y), r22 * (e1.x + e1.y));
    float2 t2 = make_float2(-e2.y, e2.x);
    float2 t3 = make_float2(-r22 * (e3.x + e3.y), r22 * (e3.x - e3.y));
    y[0] = cadd(g0, t0); y[4] = csub(g0, t0);
    y[1] = cadd(g1, t1); y[5] = csub(g1, t1);
    y[2] = cadd(g2, t2); y[6] = csub(g2, t2);
    y[3] = cadd(g3, t3); y[7] = csub(g3, t3);
}

// One block per (b,c) row, 512 threads — proven no-spill shape (VGPR 60).
// R1-R3 post-mortems: every 1024-thread variant spilled ~24-32 B/thread
// (VGPR pinned at 32, WRITE_SIZE 114-131 MB) regardless of restructure, and
// the spill stream evicted zc/zs, slowing gram. Do not revisit.
__global__ __launch_bounds__(512, 4) void fft_analytic_kernel(const float* __restrict__ x,
                                                              ushort* __restrict__ zc,
                                                              ushort* __restrict__ zs) {
    __shared__ __align__(16) float2 buf[T_LEN];   // 64 KiB
    const int tid = threadIdx.x;
    const int row = blockIdx.x;
    const float* xr = x + ((size_t)row << 13);

    // fwd pass Q=1024 fused with global load (x real; imag folds away)
    for (int s = 0; s < 2; ++s) {
        const int g = tid + (s << 9);
        float2 X[8], Y[8];
#pragma unroll
        for (int c = 0; c < 8; ++c) X[c] = make_float2(xr[g + (c << 10)], 0.f);
        float sn, cs;
        __sincosf(-(float)M_PI / 4096.f * (float)g, &sn, &cs);
        r8f(X, sn, cs, Y);
#pragma unroll
        for (int c = 0; c < 8; ++c) buf[g + (c << 10)] = Y[c];
    }
    __syncthreads();

    // fwd LDS pass Q=128
    {
        const float astep = -(float)M_PI / 512.f;
        for (int s = 0; s < 2; ++s) {
            const int g = tid + (s << 9);
            const int j = g & 127;
            const int i = ((g & ~127) << 3) | j;
            float2 xx[8], yy[8];
#pragma unroll
            for (int c = 0; c < 8; ++c) xx[c] = buf[i + c * 128];
            float sn, cs;
            __sincosf(astep * (float)j, &sn, &cs);
            r8f(xx, sn, cs, yy);
#pragma unroll
            for (int c = 0; c < 8; ++c) buf[i + c * 128] = yy[c];
        }
        __syncthreads();
    }

    // fwd LDS pass Q=16: plain reads, swizzled writes (slot = idx ^ 2c)
    {
        const float astep = -(float)M_PI / 64.f;
        for (int s = 0; s < 2; ++s) {
            const int g = tid + (s << 9);
            const int j = g & 15;
            const int i = ((g & ~15) << 3) | j;
            float2 xx[8], yy[8];
#pragma unroll
            for (int c = 0; c < 8; ++c) xx[c] = buf[i + c * 16];
            float sn, cs;
            __sincosf(astep * (float)j, &sn, &cs);
            r8f(xx, sn, cs, yy);
#pragma unroll
            for (int c = 0; c < 8; ++c) buf[(i + c * 16) ^ (2 * c)] = yy[c];
        }
        __syncthreads();
    }

    // register-local middle: thread owns elements [16*tid, 16*tid+16).
    // Element-float4 (8*tid+p) lives at slot4 (8*tid + (p^(tid&7))).
    {
        float2 v[16];
        float4* bb = (float4*)buf;
        const int K = tid & 7;
#pragma unroll
        for (int p = 0; p < 8; ++p) {
            float4 f = bb[8 * tid + (p ^ K)];
            v[2 * p]     = make_float2(f.x, f.y);
            v[2 * p + 1] = make_float2(f.z, f.w);
        }
        float2 xe[8], xo[8], E[8], O[8], t[8];
#pragma unroll
        for (int c = 0; c < 8; ++c) { xe[c] = v[2 * c]; xo[c] = v[2 * c + 1]; }
        r8f(xe, 0.f, 1.f, E);
        r8f(xo, -SIN8, COS8, O);
#pragma unroll
        for (int c = 0; c < 8; ++c) t[c] = cadd(E[c], O[c]);   // dist-1 + mask fuse
        r8i(t, 0.f, 1.f, xe);
        r8i(t, SIN8, COS8, xo);
#pragma unroll
        for (int p = 0; p < 8; ++p)
            bb[8 * tid + (p ^ K)] = make_float4(xe[p].x, xe[p].y, xo[p].x, xo[p].y);
    }
    __syncthreads();

    // inv LDS pass Q=16: swizzled reads, plain writes
    {
        const float astep = (float)M_PI / 64.f;
        for (int s = 0; s < 2; ++s) {
            const int g = tid + (s << 9);
            const int j = g & 15;
            const int i = ((g & ~15) << 3) | j;
            float2 xx[8], yy[8];
#pragma unroll
            for (int c = 0; c < 8; ++c) xx[c] = buf[(i + c * 16) ^ (2 * c)];
            float sn, cs;
            __sincosf(astep * (float)j, &sn, &cs);
            r8i(xx, sn, cs, yy);
#pragma unroll
            for (int c = 0; c < 8; ++c) buf[i + c * 16] = yy[c];
        }
        __syncthreads();
    }

    // inv LDS pass Q=128
    {
        const float astep = (float)M_PI / 512.f;
        for (int s = 0; s < 2; ++s) {
            const int g = tid + (s << 9);
            const int j = g & 127;
            const int i = ((g & ~127) << 3) | j;
            float2 xx[8], yy[8];
#pragma unroll
            for (int c = 0; c < 8; ++c) xx[c] = buf[i + c * 128];
            float sn, cs;
            __sincosf(astep * (float)j, &sn, &cs);
            r8i(xx, sn, cs, yy);
#pragma unroll
            for (int c = 0; c < 8; ++c) buf[i + c * 128] = yy[c];
        }
        __syncthreads();
    }

    // final inv pass Q=1024 fused with normalize + contiguous row-major store
    ushort* zcr = zc + ((size_t)row << 13);
    ushort* zsr = zs + ((size_t)row << 13);
    for (int s = 0; s < 2; ++s) {
        const int g = tid + (s << 9);
        float2 xx[8], yy[8];
#pragma unroll
        for (int c = 0; c < 8; ++c) xx[c] = buf[g + (c << 10)];
        float sn, cs;
        __sincosf((float)M_PI / 4096.f * (float)g, &sn, &cs);
        r8i(xx, sn, cs, yy);
#pragma unroll
        for (int c = 0; c < 8; ++c) {
            float2 vv = yy[c];
            float n2 = vv.x * vv.x + vv.y * vv.y;
            float cc = 1.f, ss = 0.f;
            if (n2 > 0.f) { float inv = rsqrtf(n2); cc = vv.x * inv; ss = vv.y * inv; }
            zcr[g + (c << 10)] = f2bf(cc);
            zsr[g + (c << 10)] = f2bf(ss);
        }
    }
}

// MFMA Gram partials. R13: grid=(BATCH, NKCHUNK=16) = 256 blocks (R12's
// NKCHUNK=32 + setprio reverted: setprio is NULL/negative on a lockstep
// 2-phase GEMM — m190 — and the extra 256 prologues + doubled partial
// traffic cost ~8 us). The real change: KSTAGE 64->128 (SROW 72->136,
// LDS 36->68 KB). Halves the barrier count per unit work (16->8 per
// block) and doubles the MFMA run-length per phase (64 MFMA between
// barriers), amortizing the 2-phase stage+barrier overhead (m233: that
// overhead is ~72% of a 2-phase loop). Bank-conflict class preserved:
// dword stride 68 = 4 mod 32, same as 36 (2-way on b128 = free, m136).
// Depth-2 prefetch + lgkm-only barriers retained (vmem never drained).
__global__ __launch_bounds__(512, 2) void gram_kernel(const ushort* __restrict__ zc,
                                                      const ushort* __restrict__ zs,
                                                      __half2* __restrict__ partial) {
    const int b = blockIdx.x, kc = blockIdx.y;
    const int tid = threadIdx.x;
    const int wave = tid >> 6;
    const int wr = wave & 3, wcol = wave >> 2;
    const int lane31 = tid & 31;
    const int half = (tid >> 5) & 1;

    __shared__ __align__(16) ushort sZ[2 * SPLANE];   // 68 KiB

    f32x16 accRe[2], accIm[2];
#pragma unroll
    for (int v = 0; v < 2; ++v)
#pragma unroll
        for (int r = 0; r < 16; ++r) { accRe[v][r] = 0.f; accIm[v][r] = 0.f; }

    const size_t base = ((size_t)b * CHN) << 13;
    const int k0 = kc << 9;   // *512 (k-chunk)

    // 8 uint4 loads/thread per tile: 512 thr * 8 * 16 B = 65536 B =
    // 2 planes * 128 rows * 128 k * 2 B.
    const ushort* srcs[8];
    int ldst[8];
#pragma unroll
    for (int q = 0; q < 8; ++q) {
        int id = tid + (q << 9);      // 0..4095 = plane*2048 + rid*16 + ck
        int plane = id >> 11;
        int pid = id & 2047;
        int rid = pid >> 4;           // 0..127
        int ck = pid & 15;            // 0..15 (8-ushort chunks)
        srcs[q] = (plane ? zs : zc) + base + ((size_t)rid << 13) + (size_t)(k0 + ck * 8);
        ldst[q] = plane * SPLANE + rid * SROW + ck * 8;
    }

    uint4 pre[2][8];
#pragma unroll
    for (int q = 0; q < 8; ++q) pre[0][q] = *(const uint4*)srcs[q];
#pragma unroll
    for (int q = 0; q < 8; ++q) pre[1][q] = *(const uint4*)(srcs[q] + KSTAGE);

#pragma unroll
    for (int it = 0; it < NITER; ++it) {
        barrier_lds_only();                         // prev iter's ds_reads done
#pragma unroll
        for (int q = 0; q < 8; ++q) *(uint4*)&sZ[ldst[q]] = pre[it & 1][q];
        if (it < NITER - 2) {
#pragma unroll
            for (int q = 0; q < 8; ++q)
                pre[it & 1][q] = *(const uint4*)(srcs[q] + (it + 2) * KSTAGE);
        }
        barrier_lds_only();                         // ds_writes visible; vmem stays in flight
#pragma unroll
        for (int kb = 0; kb < KSTAGE; kb += 16) {
            const int aoff = (wr * 32 + lane31) * SROW + kb + half * 8;
            bf16x8 aC = *(const bf16x8*)&sZ[aoff];
            bf16x8 aS = *(const bf16x8*)&sZ[SPLANE + aoff];
            bf16x8 aCn;
#pragma unroll
            for (int r = 0; r < 8; ++r) aCn[r] = (short)(aC[r] ^ (short)0x8000);
            bf16x8 bC[2], bS[2];
#pragma unroll
            for (int v = 0; v < 2; ++v) {
                const int boff = (wcol * 64 + v * 32 + lane31) * SROW + kb + half * 8;
                bC[v] = *(const bf16x8*)&sZ[boff];
                bS[v] = *(const bf16x8*)&sZ[SPLANE + boff];
            }
            accRe[0] = __builtin_amdgcn_mfma_f32_32x32x16_bf16(aC,  bC[0], accRe[0], 0, 0, 0);
            accRe[1] = __builtin_amdgcn_mfma_f32_32x32x16_bf16(aC,  bC[1], accRe[1], 0, 0, 0);
            accIm[0] = __builtin_amdgcn_mfma_f32_32x32x16_bf16(aS,  bC[0], accIm[0], 0, 0, 0);
            accIm[1] = __builtin_amdgcn_mfma_f32_32x32x16_bf16(aS,  bC[1], accIm[1], 0, 0, 0);
            accRe[0] = __builtin_amdgcn_mfma_f32_32x32x16_bf16(aS,  bS[0], accRe[0], 0, 0, 0);
            accRe[1] = __builtin_amdgcn_mfma_f32_32x32x16_bf16(aS,  bS[1], accRe[1], 0, 0, 0);
            accIm[0] = __builtin_amdgcn_mfma_f32_32x32x16_bf16(aCn, bS[0], accIm[0], 0, 0, 0);
            accIm[1] = __builtin_amdgcn_mfma_f32_32x32x16_bf16(aCn, bS[1], accIm[1], 0, 0, 0);
        }
    }

    // C/D layout (verified m74/m101): col=lane&31, row=(reg&3)+8*(reg>>2)+4*(lane>>5)
    __half2* pb = partial + ((size_t)(kc * BATCH + b) << 14);
#pragma unroll
    for (int v = 0; v < 2; ++v)
#pragma unroll
        for (int r = 0; r < 16; ++r) {
            int rrow = (r & 3) + 8 * (r >> 2) + 4 * half;
            int i = wr * 32 + rrow;
            int j = wcol * 64 + v * 32 + lane31;
            pb[i * CHN + j] = __floats2half2_rn(accRe[v][r], accIm[v][r]);
        }
}

__global__ __launch_bounds__(256) void reduce_kernel(const __half2* __restrict__ partial,
                                                     float* __restrict__ out) {
    const size_t i = (size_t)blockIdx.x * 256 + threadIdx.x;
    const size_t n = (size_t)BATCH * CHN * CHN;
    if (i >= n) return;
    float re = 0.0f, im = 0.0f;
#pragma unroll
    for (int c = 0; c < NKCHUNK; ++c) {
        float2 p = __half22float2(partial[(size_t)c * n + i]);
        re += p.x;
        im += p.y;
    }
    out[i] = sqrtf(re * re + im * im) * (1.0f / (float)T_LEN);
}

extern "C" void kernel_launch(void* const* d_in, const int* in_sizes, int n_in,
                              void* d_out, int out_size, void* d_ws, size_t ws_size,
                              hipStream_t stream) {
    const float* x = (const float*)d_in[0];
    float* out = (float*)d_out;

    const size_t plane_elems = (size_t)BATCH * CHN * T_LEN;                 // 16.8M
    ushort* zc = (ushort*)d_ws;                                             // 33.55 MB
    ushort* zs = zc + plane_elems;                                          // +33.55 MB
    __half2* partial = (__half2*)((char*)d_ws + 2 * plane_elems * sizeof(ushort)); // +16.78 MB

    fft_analytic_kernel<<<BATCH * CHN, 512, 0, stream>>>(x, zc, zs);

    dim3 g2(BATCH, NKCHUNK);
    gram_kernel<<<g2, 512, 0, stream>>>(zc, zs, partial);

    const int n_out = BATCH * CHN * CHN;
    reduce_kernel<<<(n_out + 255) / 256, 256, 0, stream>>>(partial, out);
}

// Round 6
// 184.631 us; speedup vs baseline: 1.0056x; 1.0056x over previous
//
#include <hip/hip_runtime.h>
#include <hip/hip_fp16.h>
#include <math.h>

#define T_LEN 8192
#define CHN 128
#define BATCH 16
#define NKCHUNK 32   // R14: k-chunk = 256 -> grid 16x32 = 512 blocks = 2 blocks/CU avg
#define KSTAGE 64    // k elems staged per LDS tile
#define NITER (T_LEN / NKCHUNK / KSTAGE)   // = 4 stage iterations per block

typedef short bf16x8 __attribute__((ext_vector_type(8)));
typedef float f32x16 __attribute__((ext_vector_type(16)));

#define SIN8 0.3826834323650898f
#define COS8 0.9238795325112868f
#define SROW 72          // LDS row stride (ushorts) = 144 B, 16B-aligned; dword stride 36 = 4 mod 32 (2-way, free)
#define SPLANE (128 * SROW)

__device__ __forceinline__ ushort f2bf(float f) {
    unsigned u = __float_as_uint(f);
    unsigned r = (u + 0x7fffu + ((u >> 16) & 1u)) >> 16;
    return (ushort)r;
}

// Barrier that drains ONLY LDS ops (lgkmcnt), leaving global prefetch loads
// in flight. __syncthreads() emits s_waitcnt vmcnt(0) before s_barrier, which
// would drain the depth-2 prefetch every iteration.
__device__ __forceinline__ void barrier_lds_only() {
    asm volatile("s_waitcnt lgkmcnt(0)" ::: "memory");
    __builtin_amdgcn_s_barrier();
}

__device__ __forceinline__ float2 cadd(float2 a, float2 b) { return make_float2(a.x + b.x, a.y + b.y); }
__device__ __forceinline__ float2 csub(float2 a, float2 b) { return make_float2(a.x - b.x, a.y - b.y); }
__device__ __forceinline__ float2 cmul(float2 a, float2 b) {
    return make_float2(a.x * b.x - a.y * b.y, a.x * b.y + a.y * b.x);
}

__device__ __forceinline__ void r4f(float2 x0, float2 x1, float2 x2, float2 x3,
                                    float2 wa, float2 wb, float2 wc,
                                    float2& y0, float2& y1, float2& y2, float2& y3) {
    float2 t0 = cadd(x0, x2), t1 = csub(x0, x2);
    float2 t2 = cadd(x1, x3), t3 = csub(x1, x3);
    y0 = cadd(t0, t2);
    y1 = cmul(csub(t0, t2), wb);
    y2 = cmul(make_float2(t1.x + t3.y, t1.y - t3.x), wa);
    y3 = cmul(make_float2(t1.x - t3.y, t1.y + t3.x), wc);
}

__device__ __forceinline__ void r4i(float2 x0, float2 x1, float2 x2, float2 x3,
                                    float2 wa, float2 wb, float2 wc,
                                    float2& y0, float2& y1, float2& y2, float2& y3) {
    float2 a1 = cmul(x1, wb);
    float2 a2 = cmul(x2, wa);
    float2 a3 = cmul(x3, wc);
    float2 u0 = cadd(x0, a1), u1 = csub(x0, a1);
    float2 p = cadd(a2, a3);
    float2 m = make_float2(-(a2.y - a3.y), a2.x - a3.x);
    y0 = cadd(u0, p); y2 = csub(u0, p);
    y1 = cadd(u1, m); y3 = csub(u1, m);
}

__device__ __forceinline__ void r8f(const float2* x, float sn, float cs, float2* y) {
    const float r22 = 0.70710678118654752f;
    float2 w1 = make_float2(cs, sn);
    float2 w2 = make_float2(cs * cs - sn * sn, 2.f * cs * sn);
    float2 w4 = cmul(w2, w2);
    float2 w6 = cmul(w4, w2);
    float2 u0 = cadd(x[0], x[4]), u1 = cadd(x[1], x[5]), u2 = cadd(x[2], x[6]), u3 = cadd(x[3], x[7]);
    float2 e0 = cmul(csub(x[0], x[4]), w1);
    float2 e1 = cmul(csub(x[1], x[5]), w1);
    float2 e2 = cmul(csub(x[2], x[6]), w1);
    float2 e3 = cmul(csub(x[3], x[7]), w1);
    float2 v0 = e0;
    float2 v1 = make_float2(r22 * (e1.x + e1.y), r22 * (e1.y - e1.x));
    float2 v2 = make_float2(e2.y, -e2.x);
    float2 v3 = make_float2(r22 * (e3.y - e3.x), -r22 * (e3.x + e3.y));
    r4f(u0, u1, u2, u3, w2, w4, w6, y[0], y[1], y[2], y[3]);
    r4f(v0, v1, v2, v3, w2, w4, w6, y[4], y[5], y[6], y[7]);
}

__device__ __forceinline__ void r8i(const float2* x, float sn, float cs, float2* y) {
    const float r22 = 0.70710678118654752f;
    float2 w1 = make_float2(cs, sn);
    float2 w2 = make_float2(cs * cs - sn * sn, 2.f * cs * sn);
    float2 w4 = cmul(w2, w2);
    float2 w6 = cmul(w4, w2);
    float2 g0, g1, g2, g3, g4, g5, g6, g7;
    r4i(x[0], x[1], x[2], x[3], w2, w4, w6, g0, g1, g2, g3);
    r4i(x[4], x[5], x[6], x[7], w2, w4, w6, g4, g5, g6, g7);
    float2 t0 = cmul(g4, w1);
    float2 e1 = cmul(g5, w1);
    float2 e2 = cmul(g6, w1);
    float2 e3 = cmul(g7, w1);
    float2 t1 = make_float2(r22 * (e1.x - e1.y), r22 * (e1.x + e1.y));
    float2 t2 = make_float2(-e2.y, e2.x);
    float2 t3 = make_float2(-r22 * (e3.x + e3.y), r22 * (e3.x - e3.y));
    y[0] = cadd(g0, t0); y[4] = csub(g0, t0);
    y[1] = cadd(g1, t1); y[5] = csub(g1, t1);
    y[2] = cadd(g2, t2); y[6] = csub(g2, t2);
    y[3] = cadd(g3, t3); y[7] = csub(g3, t3);
}

// One block per (b,c) row, 512 threads — proven no-spill shape (VGPR 60).
// R1-R3 post-mortems: every 1024-thread variant spilled ~24-32 B/thread
// (VGPR pinned at 32, WRITE_SIZE 114-131 MB) regardless of restructure, and
// the spill stream evicted zc/zs, slowing gram. Do not revisit.
__global__ __launch_bounds__(512, 4) void fft_analytic_kernel(const float* __restrict__ x,
                                                              ushort* __restrict__ zc,
                                                              ushort* __restrict__ zs) {
    __shared__ __align__(16) float2 buf[T_LEN];   // 64 KiB
    const int tid = threadIdx.x;
    const int row = blockIdx.x;
    const float* xr = x + ((size_t)row << 13);

    // fwd pass Q=1024 fused with global load (x real; imag folds away)
    for (int s = 0; s < 2; ++s) {
        const int g = tid + (s << 9);
        float2 X[8], Y[8];
#pragma unroll
        for (int c = 0; c < 8; ++c) X[c] = make_float2(xr[g + (c << 10)], 0.f);
        float sn, cs;
        __sincosf(-(float)M_PI / 4096.f * (float)g, &sn, &cs);
        r8f(X, sn, cs, Y);
#pragma unroll
        for (int c = 0; c < 8; ++c) buf[g + (c << 10)] = Y[c];
    }
    __syncthreads();

    // fwd LDS pass Q=128
    {
        const float astep = -(float)M_PI / 512.f;
        for (int s = 0; s < 2; ++s) {
            const int g = tid + (s << 9);
            const int j = g & 127;
            const int i = ((g & ~127) << 3) | j;
            float2 xx[8], yy[8];
#pragma unroll
            for (int c = 0; c < 8; ++c) xx[c] = buf[i + c * 128];
            float sn, cs;
            __sincosf(astep * (float)j, &sn, &cs);
            r8f(xx, sn, cs, yy);
#pragma unroll
            for (int c = 0; c < 8; ++c) buf[i + c * 128] = yy[c];
        }
        __syncthreads();
    }

    // fwd LDS pass Q=16: plain reads, swizzled writes (slot = idx ^ 2c)
    {
        const float astep = -(float)M_PI / 64.f;
        for (int s = 0; s < 2; ++s) {
            const int g = tid + (s << 9);
            const int j = g & 15;
            const int i = ((g & ~15) << 3) | j;
            float2 xx[8], yy[8];
#pragma unroll
            for (int c = 0; c < 8; ++c) xx[c] = buf[i + c * 16];
            float sn, cs;
            __sincosf(astep * (float)j, &sn, &cs);
            r8f(xx, sn, cs, yy);
#pragma unroll
            for (int c = 0; c < 8; ++c) buf[(i + c * 16) ^ (2 * c)] = yy[c];
        }
        __syncthreads();
    }

    // register-local middle: thread owns elements [16*tid, 16*tid+16).
    // Element-float4 (8*tid+p) lives at slot4 (8*tid + (p^(tid&7))).
    {
        float2 v[16];
        float4* bb = (float4*)buf;
        const int K = tid & 7;
#pragma unroll
        for (int p = 0; p < 8; ++p) {
            float4 f = bb[8 * tid + (p ^ K)];
            v[2 * p]     = make_float2(f.x, f.y);
            v[2 * p + 1] = make_float2(f.z, f.w);
        }
        float2 xe[8], xo[8], E[8], O[8], t[8];
#pragma unroll
        for (int c = 0; c < 8; ++c) { xe[c] = v[2 * c]; xo[c] = v[2 * c + 1]; }
        r8f(xe, 0.f, 1.f, E);
        r8f(xo, -SIN8, COS8, O);
#pragma unroll
        for (int c = 0; c < 8; ++c) t[c] = cadd(E[c], O[c]);   // dist-1 + mask fuse
        r8i(t, 0.f, 1.f, xe);
        r8i(t, SIN8, COS8, xo);
#pragma unroll
        for (int p = 0; p < 8; ++p)
            bb[8 * tid + (p ^ K)] = make_float4(xe[p].x, xe[p].y, xo[p].x, xo[p].y);
    }
    __syncthreads();

    // inv LDS pass Q=16: swizzled reads, plain writes
    {
        const float astep = (float)M_PI / 64.f;
        for (int s = 0; s < 2; ++s) {
            const int g = tid + (s << 9);
            const int j = g & 15;
            const int i = ((g & ~15) << 3) | j;
            float2 xx[8], yy[8];
#pragma unroll
            for (int c = 0; c < 8; ++c) xx[c] = buf[(i + c * 16) ^ (2 * c)];
            float sn, cs;
            __sincosf(astep * (float)j, &sn, &cs);
            r8i(xx, sn, cs, yy);
#pragma unroll
            for (int c = 0; c < 8; ++c) buf[i + c * 16] = yy[c];
        }
        __syncthreads();
    }

    // inv LDS pass Q=128
    {
        const float astep = (float)M_PI / 512.f;
        for (int s = 0; s < 2; ++s) {
            const int g = tid + (s << 9);
            const int j = g & 127;
            const int i = ((g & ~127) << 3) | j;
            float2 xx[8], yy[8];
#pragma unroll
            for (int c = 0; c < 8; ++c) xx[c] = buf[i + c * 128];
            float sn, cs;
            __sincosf(astep * (float)j, &sn, &cs);
            r8i(xx, sn, cs, yy);
#pragma unroll
            for (int c = 0; c < 8; ++c) buf[i + c * 128] = yy[c];
        }
        __syncthreads();
    }

    // final inv pass Q=1024 fused with normalize + contiguous row-major store
    ushort* zcr = zc + ((size_t)row << 13);
    ushort* zsr = zs + ((size_t)row << 13);
    for (int s = 0; s < 2; ++s) {
        const int g = tid + (s << 9);
        float2 xx[8], yy[8];
#pragma unroll
        for (int c = 0; c < 8; ++c) xx[c] = buf[g + (c << 10)];
        float sn, cs;
        __sincosf((float)M_PI / 4096.f * (float)g, &sn, &cs);
        r8i(xx, sn, cs, yy);
#pragma unroll
        for (int c = 0; c < 8; ++c) {
            float2 vv = yy[c];
            float n2 = vv.x * vv.x + vv.y * vv.y;
            float cc = 1.f, ss = 0.f;
            if (n2 > 0.f) { float inv = rsqrtf(n2); cc = vv.x * inv; ss = vv.y * inv; }
            zcr[g + (c << 10)] = f2bf(cc);
            zsr[g + (c << 10)] = f2bf(ss);
        }
    }
}

// MFMA Gram partials. R14: grid=(BATCH, NKCHUNK=32) = 512 blocks = 2/CU avg
// (LDS 36 KB and 64 VGPR allow up to 4 resident). R5 showed that at 1
// block/CU every barrier is a full-CU stall (KSTAGE=128's halved barrier
// count bought nothing); the m97-structure's efficiency comes from implicit
// CROSS-BLOCK wave overlap at >=2 blocks/CU (m114). The k-split does not
// duplicate zc/zs reads (each block reads 128 rows x its own k-range).
// NO s_setprio (m190: null-to-negative on lockstep barrier-synced GEMM —
// it was confounded into R4/R12). Depth-2 prefetch + lgkm-only barriers.
__global__ __launch_bounds__(512, 2) void gram_kernel(const ushort* __restrict__ zc,
                                                      const ushort* __restrict__ zs,
                                                      __half2* __restrict__ partial) {
    const int b = blockIdx.x, kc = blockIdx.y;
    const int tid = threadIdx.x;
    const int wave = tid >> 6;
    const int wr = wave & 3, wcol = wave >> 2;
    const int lane31 = tid & 31;
    const int half = (tid >> 5) & 1;

    __shared__ __align__(16) ushort sZ[2 * SPLANE];   // 36 KiB

    f32x16 accRe[2], accIm[2];
#pragma unroll
    for (int v = 0; v < 2; ++v)
#pragma unroll
        for (int r = 0; r < 16; ++r) { accRe[v][r] = 0.f; accIm[v][r] = 0.f; }

    const size_t base = ((size_t)b * CHN) << 13;
    const int k0 = kc << 8;   // *256 (k-chunk)

    const ushort* srcs[4];
    int ldst[4];
#pragma unroll
    for (int q = 0; q < 4; ++q) {
        int id = tid + (q << 9);                   // 0..2047 = plane*1024 + rid*8 + ck
        int plane = id >> 10;
        int rid = (id >> 3) & 127;
        int ck = id & 7;
        srcs[q] = (plane ? zs : zc) + base + ((size_t)rid << 13) + (size_t)(k0 + ck * 8);
        ldst[q] = plane * SPLANE + rid * SROW + ck * 8;
    }

    uint4 pre[2][4];
#pragma unroll
    for (int q = 0; q < 4; ++q) pre[0][q] = *(const uint4*)srcs[q];
#pragma unroll
    for (int q = 0; q < 4; ++q) pre[1][q] = *(const uint4*)(srcs[q] + KSTAGE);

#pragma unroll
    for (int it = 0; it < NITER; ++it) {
        barrier_lds_only();                         // prev iter's ds_reads done
#pragma unroll
        for (int q = 0; q < 4; ++q) *(uint4*)&sZ[ldst[q]] = pre[it & 1][q];
        if (it < NITER - 2) {
#pragma unroll
            for (int q = 0; q < 4; ++q)
                pre[it & 1][q] = *(const uint4*)(srcs[q] + (it + 2) * KSTAGE);
        }
        barrier_lds_only();                         // ds_writes visible; vmem stays in flight
#pragma unroll
        for (int kb = 0; kb < KSTAGE; kb += 16) {
            const int aoff = (wr * 32 + lane31) * SROW + kb + half * 8;
            bf16x8 aC = *(const bf16x8*)&sZ[aoff];
            bf16x8 aS = *(const bf16x8*)&sZ[SPLANE + aoff];
            bf16x8 aCn;
#pragma unroll
            for (int r = 0; r < 8; ++r) aCn[r] = (short)(aC[r] ^ (short)0x8000);
            bf16x8 bC[2], bS[2];
#pragma unroll
            for (int v = 0; v < 2; ++v) {
                const int boff = (wcol * 64 + v * 32 + lane31) * SROW + kb + half * 8;
                bC[v] = *(const bf16x8*)&sZ[boff];
                bS[v] = *(const bf16x8*)&sZ[SPLANE + boff];
            }
            accRe[0] = __builtin_amdgcn_mfma_f32_32x32x16_bf16(aC,  bC[0], accRe[0], 0, 0, 0);
            accRe[1] = __builtin_amdgcn_mfma_f32_32x32x16_bf16(aC,  bC[1], accRe[1], 0, 0, 0);
            accIm[0] = __builtin_amdgcn_mfma_f32_32x32x16_bf16(aS,  bC[0], accIm[0], 0, 0, 0);
            accIm[1] = __builtin_amdgcn_mfma_f32_32x32x16_bf16(aS,  bC[1], accIm[1], 0, 0, 0);
            accRe[0] = __builtin_amdgcn_mfma_f32_32x32x16_bf16(aS,  bS[0], accRe[0], 0, 0, 0);
            accRe[1] = __builtin_amdgcn_mfma_f32_32x32x16_bf16(aS,  bS[1], accRe[1], 0, 0, 0);
            accIm[0] = __builtin_amdgcn_mfma_f32_32x32x16_bf16(aCn, bS[0], accIm[0], 0, 0, 0);
            accIm[1] = __builtin_amdgcn_mfma_f32_32x32x16_bf16(aCn, bS[1], accIm[1], 0, 0, 0);
        }
    }

    // C/D layout (verified m74/m101): col=lane&31, row=(reg&3)+8*(reg>>2)+4*(lane>>5)
    __half2* pb = partial + ((size_t)(kc * BATCH + b) << 14);
#pragma unroll
    for (int v = 0; v < 2; ++v)
#pragma unroll
        for (int r = 0; r < 16; ++r) {
            int rrow = (r & 3) + 8 * (r >> 2) + 4 * half;
            int i = wr * 32 + rrow;
            int j = wcol * 64 + v * 32 + lane31;
            pb[i * CHN + j] = __floats2half2_rn(accRe[v][r], accIm[v][r]);
        }
}

__global__ __launch_bounds__(256) void reduce_kernel(const __half2* __restrict__ partial,
                                                     float* __restrict__ out) {
    const size_t i = (size_t)blockIdx.x * 256 + threadIdx.x;
    const size_t n = (size_t)BATCH * CHN * CHN;
    if (i >= n) return;
    float re = 0.0f, im = 0.0f;
#pragma unroll
    for (int c = 0; c < NKCHUNK; ++c) {
        float2 p = __half22float2(partial[(size_t)c * n + i]);
        re += p.x;
        im += p.y;
    }
    out[i] = sqrtf(re * re + im * im) * (1.0f / (float)T_LEN);
}

extern "C" void kernel_launch(void* const* d_in, const int* in_sizes, int n_in,
                              void* d_out, int out_size, void* d_ws, size_t ws_size,
                              hipStream_t stream) {
    const float* x = (const float*)d_in[0];
    float* out = (float*)d_out;

    const size_t plane_elems = (size_t)BATCH * CHN * T_LEN;                 // 16.8M
    ushort* zc = (ushort*)d_ws;                                             // 33.55 MB
    ushort* zs = zc + plane_elems;                                          // +33.55 MB
    __half2* partial = (__half2*)((char*)d_ws + 2 * plane_elems * sizeof(ushort)); // +33.55 MB (NKCHUNK=32)

    fft_analytic_kernel<<<BATCH * CHN, 512, 0, stream>>>(x, zc, zs);

    dim3 g2(BATCH, NKCHUNK);
    gram_kernel<<<g2, 512, 0, stream>>>(zc, zs, partial);

    const int n_out = BATCH * CHN * CHN;
    reduce_kernel<<<(n_out + 255) / 256, 256, 0, stream>>>(partial, out);
}

// Round 7
// 176.511 us; speedup vs baseline: 1.0519x; 1.0460x over previous
//
#include <hip/hip_runtime.h>
#include <hip/hip_fp16.h>
#include <math.h>

#define T_LEN 8192
#define CHN 128
#define BATCH 16
#define NKCHUNK 32   // k-chunk = 256 -> grid 16x32 = 512 blocks (2 resident/CU)
#define KSTAGE 64    // k elems staged per LDS buffer
#define NITER (T_LEN / NKCHUNK / KSTAGE)   // = 4 stage iterations per block

typedef short bf16x8 __attribute__((ext_vector_type(8)));
typedef float f32x16 __attribute__((ext_vector_type(16)));

#define SIN8 0.3826834323650898f
#define COS8 0.9238795325112868f

// R15 gram LDS geometry: UNPADDED rows (required by global_load_lds linear
// dest) + XOR swizzle. Row = 64 ushorts = 128 B = 8 chunks of 16 B.
// Chunk c of row r lives at slot (c ^ (r&7)) — both-sides-or-neither
// (rule #21): staging permutes the per-lane GLOBAL source by the same
// involution, LDS dest stays linear, MFMA reads apply the XOR.
#define KROW 64                  // ushorts per row
#define SPLANE (128 * KROW)      // 8192 ushorts = 16 KiB per plane
#define BUFSZ (2 * SPLANE)       // 16384 ushorts = 32 KiB per buffer (zc+zs planes)

typedef const __attribute__((address_space(1))) uint gld_src_t;
typedef __attribute__((address_space(3))) uint gld_dst_t;

__device__ __forceinline__ ushort f2bf(float f) {
    unsigned u = __float_as_uint(f);
    unsigned r = (u + 0x7fffu + ((u >> 16) & 1u)) >> 16;
    return (ushort)r;
}

// Barrier that drains ONLY LDS ops (lgkmcnt), leaving global/DMA loads in
// flight. __syncthreads() would emit s_waitcnt vmcnt(0) before s_barrier.
__device__ __forceinline__ void barrier_lds_only() {
    asm volatile("s_waitcnt lgkmcnt(0)" ::: "memory");
    __builtin_amdgcn_s_barrier();
}

__device__ __forceinline__ float2 cadd(float2 a, float2 b) { return make_float2(a.x + b.x, a.y + b.y); }
__device__ __forceinline__ float2 csub(float2 a, float2 b) { return make_float2(a.x - b.x, a.y - b.y); }
__device__ __forceinline__ float2 cmul(float2 a, float2 b) {
    return make_float2(a.x * b.x - a.y * b.y, a.x * b.y + a.y * b.x);
}

__device__ __forceinline__ void r4f(float2 x0, float2 x1, float2 x2, float2 x3,
                                    float2 wa, float2 wb, float2 wc,
                                    float2& y0, float2& y1, float2& y2, float2& y3) {
    float2 t0 = cadd(x0, x2), t1 = csub(x0, x2);
    float2 t2 = cadd(x1, x3), t3 = csub(x1, x3);
    y0 = cadd(t0, t2);
    y1 = cmul(csub(t0, t2), wb);
    y2 = cmul(make_float2(t1.x + t3.y, t1.y - t3.x), wa);
    y3 = cmul(make_float2(t1.x - t3.y, t1.y + t3.x), wc);
}

__device__ __forceinline__ void r4i(float2 x0, float2 x1, float2 x2, float2 x3,
                                    float2 wa, float2 wb, float2 wc,
                                    float2& y0, float2& y1, float2& y2, float2& y3) {
    float2 a1 = cmul(x1, wb);
    float2 a2 = cmul(x2, wa);
    float2 a3 = cmul(x3, wc);
    float2 u0 = cadd(x0, a1), u1 = csub(x0, a1);
    float2 p = cadd(a2, a3);
    float2 m = make_float2(-(a2.y - a3.y), a2.x - a3.x);
    y0 = cadd(u0, p); y2 = csub(u0, p);
    y1 = cadd(u1, m); y3 = csub(u1, m);
}

__device__ __forceinline__ void r8f(const float2* x, float sn, float cs, float2* y) {
    const float r22 = 0.70710678118654752f;
    float2 w1 = make_float2(cs, sn);
    float2 w2 = make_float2(cs * cs - sn * sn, 2.f * cs * sn);
    float2 w4 = cmul(w2, w2);
    float2 w6 = cmul(w4, w2);
    float2 u0 = cadd(x[0], x[4]), u1 = cadd(x[1], x[5]), u2 = cadd(x[2], x[6]), u3 = cadd(x[3], x[7]);
    float2 e0 = cmul(csub(x[0], x[4]), w1);
    float2 e1 = cmul(csub(x[1], x[5]), w1);
    float2 e2 = cmul(csub(x[2], x[6]), w1);
    float2 e3 = cmul(csub(x[3], x[7]), w1);
    float2 v0 = e0;
    float2 v1 = make_float2(r22 * (e1.x + e1.y), r22 * (e1.y - e1.x));
    float2 v2 = make_float2(e2.y, -e2.x);
    float2 v3 = make_float2(r22 * (e3.y - e3.x), -r22 * (e3.x + e3.y));
    r4f(u0, u1, u2, u3, w2, w4, w6, y[0], y[1], y[2], y[3]);
    r4f(v0, v1, v2, v3, w2, w4, w6, y[4], y[5], y[6], y[7]);
}

__device__ __forceinline__ void r8i(const float2* x, float sn, float cs, float2* y) {
    const float r22 = 0.70710678118654752f;
    float2 w1 = make_float2(cs, sn);
    float2 w2 = make_float2(cs * cs - sn * sn, 2.f * cs * sn);
    float2 w4 = cmul(w2, w2);
    float2 w6 = cmul(w4, w2);
    float2 g0, g1, g2, g3, g4, g5, g6, g7;
    r4i(x[0], x[1], x[2], x[3], w2, w4, w6, g0, g1, g2, g3);
    r4i(x[4], x[5], x[6], x[7], w2, w4, w6, g4, g5, g6, g7);
    float2 t0 = cmul(g4, w1);
    float2 e1 = cmul(g5, w1);
    float2 e2 = cmul(g6, w1);
    float2 e3 = cmul(g7, w1);
    float2 t1 = make_float2(r22 * (e1.x - e1.y), r22 * (e1.x + e1.y));
    float2 t2 = make_float2(-e2.y, e2.x);
    float2 t3 = make_float2(-r22 * (e3.x + e3.y), r22 * (e3.x - e3.y));
    y[0] = cadd(g0, t0); y[4] = csub(g0, t0);
    y[1] = cadd(g1, t1); y[5] = csub(g1, t1);
    y[2] = cadd(g2, t2); y[6] = csub(g2, t2);
    y[3] = cadd(g3, t3); y[7] = csub(g3, t3);
}

// One block per (b,c) row, 512 threads — proven no-spill shape (VGPR 60).
// R1-R3: every 1024-thread variant spilled regardless of restructure. Do not
// revisit. UNCHANGED from R4/R5/R6.
__global__ __launch_bounds__(512, 4) void fft_analytic_kernel(const float* __restrict__ x,
                                                              ushort* __restrict__ zc,
                                                              ushort* __restrict__ zs) {
    __shared__ __align__(16) float2 buf[T_LEN];   // 64 KiB
    const int tid = threadIdx.x;
    const int row = blockIdx.x;
    const float* xr = x + ((size_t)row << 13);

    // fwd pass Q=1024 fused with global load (x real; imag folds away)
    for (int s = 0; s < 2; ++s) {
        const int g = tid + (s << 9);
        float2 X[8], Y[8];
#pragma unroll
        for (int c = 0; c < 8; ++c) X[c] = make_float2(xr[g + (c << 10)], 0.f);
        float sn, cs;
        __sincosf(-(float)M_PI / 4096.f * (float)g, &sn, &cs);
        r8f(X, sn, cs, Y);
#pragma unroll
        for (int c = 0; c < 8; ++c) buf[g + (c << 10)] = Y[c];
    }
    __syncthreads();

    // fwd LDS pass Q=128
    {
        const float astep = -(float)M_PI / 512.f;
        for (int s = 0; s < 2; ++s) {
            const int g = tid + (s << 9);
            const int j = g & 127;
            const int i = ((g & ~127) << 3) | j;
            float2 xx[8], yy[8];
#pragma unroll
            for (int c = 0; c < 8; ++c) xx[c] = buf[i + c * 128];
            float sn, cs;
            __sincosf(astep * (float)j, &sn, &cs);
            r8f(xx, sn, cs, yy);
#pragma unroll
            for (int c = 0; c < 8; ++c) buf[i + c * 128] = yy[c];
        }
        __syncthreads();
    }

    // fwd LDS pass Q=16: plain reads, swizzled writes (slot = idx ^ 2c)
    {
        const float astep = -(float)M_PI / 64.f;
        for (int s = 0; s < 2; ++s) {
            const int g = tid + (s << 9);
            const int j = g & 15;
            const int i = ((g & ~15) << 3) | j;
            float2 xx[8], yy[8];
#pragma unroll
            for (int c = 0; c < 8; ++c) xx[c] = buf[i + c * 16];
            float sn, cs;
            __sincosf(astep * (float)j, &sn, &cs);
            r8f(xx, sn, cs, yy);
#pragma unroll
            for (int c = 0; c < 8; ++c) buf[(i + c * 16) ^ (2 * c)] = yy[c];
        }
        __syncthreads();
    }

    // register-local middle: thread owns elements [16*tid, 16*tid+16).
    // Element-float4 (8*tid+p) lives at slot4 (8*tid + (p^(tid&7))).
    {
        float2 v[16];
        float4* bb = (float4*)buf;
        const int K = tid & 7;
#pragma unroll
        for (int p = 0; p < 8; ++p) {
            float4 f = bb[8 * tid + (p ^ K)];
            v[2 * p]     = make_float2(f.x, f.y);
            v[2 * p + 1] = make_float2(f.z, f.w);
        }
        float2 xe[8], xo[8], E[8], O[8], t[8];
#pragma unroll
        for (int c = 0; c < 8; ++c) { xe[c] = v[2 * c]; xo[c] = v[2 * c + 1]; }
        r8f(xe, 0.f, 1.f, E);
        r8f(xo, -SIN8, COS8, O);
#pragma unroll
        for (int c = 0; c < 8; ++c) t[c] = cadd(E[c], O[c]);   // dist-1 + mask fuse
        r8i(t, 0.f, 1.f, xe);
        r8i(t, SIN8, COS8, xo);
#pragma unroll
        for (int p = 0; p < 8; ++p)
            bb[8 * tid + (p ^ K)] = make_float4(xe[p].x, xe[p].y, xo[p].x, xo[p].y);
    }
    __syncthreads();

    // inv LDS pass Q=16: swizzled reads, plain writes
    {
        const float astep = (float)M_PI / 64.f;
        for (int s = 0; s < 2; ++s) {
            const int g = tid + (s << 9);
            const int j = g & 15;
            const int i = ((g & ~15) << 3) | j;
            float2 xx[8], yy[8];
#pragma unroll
            for (int c = 0; c < 8; ++c) xx[c] = buf[(i + c * 16) ^ (2 * c)];
            float sn, cs;
            __sincosf(astep * (float)j, &sn, &cs);
            r8i(xx, sn, cs, yy);
#pragma unroll
            for (int c = 0; c < 8; ++c) buf[i + c * 16] = yy[c];
        }
        __syncthreads();
    }

    // inv LDS pass Q=128
    {
        const float astep = (float)M_PI / 512.f;
        for (int s = 0; s < 2; ++s) {
            const int g = tid + (s << 9);
            const int j = g & 127;
            const int i = ((g & ~127) << 3) | j;
            float2 xx[8], yy[8];
#pragma unroll
            for (int c = 0; c < 8; ++c) xx[c] = buf[i + c * 128];
            float sn, cs;
            __sincosf(astep * (float)j, &sn, &cs);
            r8i(xx, sn, cs, yy);
#pragma unroll
            for (int c = 0; c < 8; ++c) buf[i + c * 128] = yy[c];
        }
        __syncthreads();
    }

    // final inv pass Q=1024 fused with normalize + contiguous row-major store
    ushort* zcr = zc + ((size_t)row << 13);
    ushort* zsr = zs + ((size_t)row << 13);
    for (int s = 0; s < 2; ++s) {
        const int g = tid + (s << 9);
        float2 xx[8], yy[8];
#pragma unroll
        for (int c = 0; c < 8; ++c) xx[c] = buf[g + (c << 10)];
        float sn, cs;
        __sincosf((float)M_PI / 4096.f * (float)g, &sn, &cs);
        r8i(xx, sn, cs, yy);
#pragma unroll
        for (int c = 0; c < 8; ++c) {
            float2 vv = yy[c];
            float n2 = vv.x * vv.x + vv.y * vv.y;
            float cc = 1.f, ss = 0.f;
            if (n2 > 0.f) { float inv = rsqrtf(n2); cc = vv.x * inv; ss = vv.y * inv; }
            zcr[g + (c << 10)] = f2bf(cc);
            zsr[g + (c << 10)] = f2bf(ss);
        }
    }
}

// MFMA Gram partials — R15 full restructure. R6 counters: MfmaUtil 0.28%,
// VALUBusy 0.11% at 136 us = waves ~99.7% stalled in vmcnt waits; the
// depth-2 REGISTER prefetch covers only ~2 iters of HBM latency and the
// loop is 4-8 iters, so it never leaves its prologue. Fix = T3/T4 minimum
// 2-phase with global_load_lds (async DMA, no VGPR round-trip) + counted
// vmcnt(4) (never 0 in steady state) + double-buffered LDS:
//   iter: vmcnt(4) -> s_barrier -> MFMA from buf[p] -> lgkm-barrier
//         -> DMA-stage buf[p] for it+2
// LDS dest must be linear (m104), so bank-decorrelation uses the
// pre-swizzled-global-source pattern (m173/rule #21): chunk c of row r is
// stored at slot c^(r&7); the staging lane for slot s of row r loads global
// chunk s^(r&7) (the 8 lanes of a row still cover the same 128 B — 
// coalescing unchanged); MFMA reads apply the same XOR. b128 A/B reads are
// 4-way conflicts (8-slot spread over 32 rows) — same class as the old
// padded SROW=72 layout. VGPR: no pre[] regs -> ~115; launch_bounds(512,4)
// (128 budget) keeps 2 blocks/CU with 64 KiB LDS each.
__global__ __launch_bounds__(512, 4) void gram_kernel(const ushort* __restrict__ zc,
                                                      const ushort* __restrict__ zs,
                                                      __half2* __restrict__ partial) {
    const int b = blockIdx.x, kc = blockIdx.y;
    const int tid = threadIdx.x;
    const int wave = tid >> 6;
    const int lane = tid & 63;
    const int wr = wave & 3, wcol = wave >> 2;
    const int lane31 = tid & 31;
    const int half = (tid >> 5) & 1;

    __shared__ __align__(16) ushort sZ[2 * BUFSZ];   // 64 KiB: 2 x (2 planes x 128 rows x 64 k)

    f32x16 accRe[2], accIm[2];
#pragma unroll
    for (int v = 0; v < 2; ++v)
#pragma unroll
        for (int r = 0; r < 16; ++r) { accRe[v][r] = 0.f; accIm[v][r] = 0.f; }

    const size_t base = ((size_t)b * CHN) << 13;
    const int k0 = kc << 8;   // *256 (k-chunk)

    // Staging decode: wave-issue q covers linear chunks L=(q*8+wave)*64+lane.
    // L = plane*1024 + r*8 + slot; the DATA for slot is global chunk
    // c = slot ^ (r&7). LDS dest is wave-uniform base + lane*16 (HW).
    const ushort* gsrc[4];
    int lbase[4];
#pragma unroll
    for (int q = 0; q < 4; ++q) {
        int L = (q * 8 + wave) * 64 + lane;
        int plane = L >> 10;
        int r = (L >> 3) & 127;
        int slot = L & 7;
        int c = slot ^ (r & 7);
        gsrc[q] = (plane ? zs : zc) + base + ((size_t)r << 13) + (size_t)(k0 + c * 8);
        lbase[q] = (q * 8 + wave) * 512;   // ushort offset of the 1 KiB wave-issue group
    }

#define STAGE(IT, BUF) do {                                                        \
        _Pragma("unroll")                                                          \
        for (int q = 0; q < 4; ++q)                                                \
            __builtin_amdgcn_global_load_lds(                                      \
                (gld_src_t*)(gsrc[q] + (IT) * KSTAGE),                             \
                (gld_dst_t*)&sZ[(BUF) * BUFSZ + lbase[q]], 16, 0, 0);              \
    } while (0)

    STAGE(0, 0);
    STAGE(1, 1);

#pragma unroll
    for (int it = 0; it < NITER; ++it) {
        // counted vmcnt: wait only for buf[it&1]'s 4 DMAs (oldest); the next
        // buffer's 4 stay in flight across the barrier (T4 — never drain to 0
        // except the tail iteration).
        if (it < NITER - 1) { asm volatile("s_waitcnt vmcnt(4)" ::: "memory"); }
        else                { asm volatile("s_waitcnt vmcnt(0)" ::: "memory"); }
        __builtin_amdgcn_sched_barrier(0);
        __builtin_amdgcn_s_barrier();

        const ushort* S = sZ + (it & 1) * BUFSZ;
#pragma unroll
        for (int kb = 0; kb < KSTAGE; kb += 16) {
            const int cA = (kb >> 3) + half;                       // chunk 0..7
            const int rowA = wr * 32 + lane31;
            const int aoff = rowA * KROW + ((cA ^ (rowA & 7)) << 3);
            bf16x8 aC = *(const bf16x8*)&S[aoff];
            bf16x8 aS = *(const bf16x8*)&S[SPLANE + aoff];
            bf16x8 aCn;
#pragma unroll
            for (int r = 0; r < 8; ++r) aCn[r] = (short)(aC[r] ^ (short)0x8000);
            bf16x8 bC[2], bS[2];
#pragma unroll
            for (int v = 0; v < 2; ++v) {
                const int rowB = wcol * 64 + v * 32 + lane31;
                const int boff = rowB * KROW + ((cA ^ (rowB & 7)) << 3);
                bC[v] = *(const bf16x8*)&S[boff];
                bS[v] = *(const bf16x8*)&S[SPLANE + boff];
            }
            accRe[0] = __builtin_amdgcn_mfma_f32_32x32x16_bf16(aC,  bC[0], accRe[0], 0, 0, 0);
            accRe[1] = __builtin_amdgcn_mfma_f32_32x32x16_bf16(aC,  bC[1], accRe[1], 0, 0, 0);
            accIm[0] = __builtin_amdgcn_mfma_f32_32x32x16_bf16(aS,  bC[0], accIm[0], 0, 0, 0);
            accIm[1] = __builtin_amdgcn_mfma_f32_32x32x16_bf16(aS,  bC[1], accIm[1], 0, 0, 0);
            accRe[0] = __builtin_amdgcn_mfma_f32_32x32x16_bf16(aS,  bS[0], accRe[0], 0, 0, 0);
            accRe[1] = __builtin_amdgcn_mfma_f32_32x32x16_bf16(aS,  bS[1], accRe[1], 0, 0, 0);
            accIm[0] = __builtin_amdgcn_mfma_f32_32x32x16_bf16(aCn, bS[0], accIm[0], 0, 0, 0);
            accIm[1] = __builtin_amdgcn_mfma_f32_32x32x16_bf16(aCn, bS[1], accIm[1], 0, 0, 0);
        }

        // all waves done READING buf[it&1] (drain own lgkm, then sync) before
        // the DMA for it+2 overwrites it. vmem stays in flight.
        barrier_lds_only();
        if (it + 2 < NITER) STAGE(it + 2, it & 1);
    }
#undef STAGE

    // C/D layout (verified m74/m101): col=lane&31, row=(reg&3)+8*(reg>>2)+4*(lane>>5)
    __half2* pb = partial + ((size_t)(kc * BATCH + b) << 14);
#pragma unroll
    for (int v = 0; v < 2; ++v)
#pragma unroll
        for (int r = 0; r < 16; ++r) {
            int rrow = (r & 3) + 8 * (r >> 2) + 4 * half;
            int i = wr * 32 + rrow;
            int j = wcol * 64 + v * 32 + lane31;
            pb[i * CHN + j] = __floats2half2_rn(accRe[v][r], accIm[v][r]);
        }
}

__global__ __launch_bounds__(256) void reduce_kernel(const __half2* __restrict__ partial,
                                                     float* __restrict__ out) {
    const size_t i = (size_t)blockIdx.x * 256 + threadIdx.x;
    const size_t n = (size_t)BATCH * CHN * CHN;
    if (i >= n) return;
    float re = 0.0f, im = 0.0f;
#pragma unroll
    for (int c = 0; c < NKCHUNK; ++c) {
        float2 p = __half22float2(partial[(size_t)c * n + i]);
        re += p.x;
        im += p.y;
    }
    out[i] = sqrtf(re * re + im * im) * (1.0f / (float)T_LEN);
}

extern "C" void kernel_launch(void* const* d_in, const int* in_sizes, int n_in,
                              void* d_out, int out_size, void* d_ws, size_t ws_size,
                              hipStream_t stream) {
    const float* x = (const float*)d_in[0];
    float* out = (float*)d_out;

    const size_t plane_elems = (size_t)BATCH * CHN * T_LEN;                 // 16.8M
    ushort* zc = (ushort*)d_ws;                                             // 33.55 MB
    ushort* zs = zc + plane_elems;                                          // +33.55 MB
    __half2* partial = (__half2*)((char*)d_ws + 2 * plane_elems * sizeof(ushort)); // +33.55 MB (NKCHUNK=32)

    fft_analytic_kernel<<<BATCH * CHN, 512, 0, stream>>>(x, zc, zs);

    dim3 g2(BATCH, NKCHUNK);
    gram_kernel<<<g2, 512, 0, stream>>>(zc, zs, partial);

    const int n_out = BATCH * CHN * CHN;
    reduce_kernel<<<(n_out + 255) / 256, 256, 0, stream>>>(partial, out);
}

// Round 8
// 172.229 us; speedup vs baseline: 1.0781x; 1.0249x over previous
//
#include <hip/hip_runtime.h>
#include <hip/hip_fp16.h>
#include <math.h>

#define T_LEN 8192
#define CHN 128
#define BATCH 16
#define NKCHUNK 32   // k-chunk = 256 -> grid 16x32 = 512 blocks (2 resident/CU)
#define KSTAGE 64    // k elems staged per LDS buffer
#define NITER (T_LEN / NKCHUNK / KSTAGE)   // = 4 stage iterations per block

typedef short bf16x8 __attribute__((ext_vector_type(8)));
typedef float f32x16 __attribute__((ext_vector_type(16)));

// R16: native-vector complex type. HIP's float2 is a struct -> scalar
// v_add_f32 codegen; ext_vector <2 x float> arithmetic selects packed
// v_pk_add_f32 / v_pk_mul_f32 / v_pk_fma_f32 (full-rate on CDNA2+),
// halving the instruction count of every complex add/sub.
typedef float cplx __attribute__((ext_vector_type(2)));
__device__ __forceinline__ cplx C2(float x, float y) { cplx r; r.x = x; r.y = y; return r; }

#define SIN8 0.3826834323650898f
#define COS8 0.9238795325112868f

// gram LDS geometry (R15, unchanged): UNPADDED rows + XOR swizzle.
#define KROW 64                  // ushorts per row
#define SPLANE (128 * KROW)      // 16 KiB per plane
#define BUFSZ (2 * SPLANE)       // 32 KiB per buffer (zc+zs planes)

typedef const __attribute__((address_space(1))) uint gld_src_t;
typedef __attribute__((address_space(3))) uint gld_dst_t;

__device__ __forceinline__ ushort f2bf(float f) {
    unsigned u = __float_as_uint(f);
    unsigned r = (u + 0x7fffu + ((u >> 16) & 1u)) >> 16;
    return (ushort)r;
}

__device__ __forceinline__ void barrier_lds_only() {
    asm volatile("s_waitcnt lgkmcnt(0)" ::: "memory");
    __builtin_amdgcn_s_barrier();
}

__device__ __forceinline__ cplx cmul(cplx a, cplx b) {
    cplx t = a.yy * b.yx;            // {ay*by, ay*bx}  (pk_mul)
    cplx r = a.xx * b;               // {ax*bx, ax*by}  (pk_mul)
    return C2(r.x - t.x, r.y + t.y); // fsub/fadd fuse into fma per lane
}

__device__ __forceinline__ void r4f(cplx x0, cplx x1, cplx x2, cplx x3,
                                    cplx wa, cplx wb, cplx wc,
                                    cplx& y0, cplx& y1, cplx& y2, cplx& y3) {
    cplx t0 = x0 + x2, t1 = x0 - x2;
    cplx t2 = x1 + x3, t3 = x1 - x3;
    y0 = t0 + t2;
    y1 = cmul(t0 - t2, wb);
    y2 = cmul(C2(t1.x + t3.y, t1.y - t3.x), wa);
    y3 = cmul(C2(t1.x - t3.y, t1.y + t3.x), wc);
}

__device__ __forceinline__ void r4i(cplx x0, cplx x1, cplx x2, cplx x3,
                                    cplx wa, cplx wb, cplx wc,
                                    cplx& y0, cplx& y1, cplx& y2, cplx& y3) {
    cplx a1 = cmul(x1, wb);
    cplx a2 = cmul(x2, wa);
    cplx a3 = cmul(x3, wc);
    cplx u0 = x0 + a1, u1 = x0 - a1;
    cplx p = a2 + a3;
    cplx m = C2(-(a2.y - a3.y), a2.x - a3.x);
    y0 = u0 + p; y2 = u0 - p;
    y1 = u1 + m; y3 = u1 - m;
}

__device__ __forceinline__ void r8f(const cplx* x, float sn, float cs, cplx* y) {
    const float r22 = 0.70710678118654752f;
    cplx w1 = C2(cs, sn);
    cplx w2 = C2(cs * cs - sn * sn, 2.f * cs * sn);
    cplx w4 = cmul(w2, w2);
    cplx w6 = cmul(w4, w2);
    cplx u0 = x[0] + x[4], u1 = x[1] + x[5], u2 = x[2] + x[6], u3 = x[3] + x[7];
    cplx e0 = cmul(x[0] - x[4], w1);
    cplx e1 = cmul(x[1] - x[5], w1);
    cplx e2 = cmul(x[2] - x[6], w1);
    cplx e3 = cmul(x[3] - x[7], w1);
    cplx v0 = e0;
    cplx v1 = C2(r22 * (e1.x + e1.y), r22 * (e1.y - e1.x));
    cplx v2 = C2(e2.y, -e2.x);
    cplx v3 = C2(r22 * (e3.y - e3.x), -r22 * (e3.x + e3.y));
    r4f(u0, u1, u2, u3, w2, w4, w6, y[0], y[1], y[2], y[3]);
    r4f(v0, v1, v2, v3, w2, w4, w6, y[4], y[5], y[6], y[7]);
}

// Pass-A specialization: inputs pure real (imag = 0). Verified correct in
// R2's passing run. Halves pass-A live registers and strips dead-imag VALU.
__device__ __forceinline__ void r8f_real(const float* x, float sn, float cs, cplx* y) {
    const float r22 = 0.70710678118654752f;
    cplx w2 = C2(cs * cs - sn * sn, 2.f * cs * sn);
    cplx w4 = cmul(w2, w2);
    cplx w6 = cmul(w4, w2);
    float u0 = x[0] + x[4], u1 = x[1] + x[5], u2 = x[2] + x[6], u3 = x[3] + x[7];
    float d0 = x[0] - x[4], d1 = x[1] - x[5], d2 = x[2] - x[6], d3 = x[3] - x[7];
    cplx e1 = C2(d1 * cs, d1 * sn);
    cplx e2 = C2(d2 * cs, d2 * sn);
    cplx e3 = C2(d3 * cs, d3 * sn);
    cplx v0 = C2(d0 * cs, d0 * sn);
    cplx v1 = C2(r22 * (e1.x + e1.y), r22 * (e1.y - e1.x));
    cplx v2 = C2(e2.y, -e2.x);
    cplx v3 = C2(r22 * (e3.y - e3.x), -r22 * (e3.x + e3.y));
    float t0 = u0 + u2, t1 = u0 - u2, t2 = u1 + u3, t3 = u1 - u3;
    y[0] = C2(t0 + t2, 0.f);
    float s1 = t0 - t2;
    y[1] = C2(s1 * w4.x, s1 * w4.y);
    y[2] = cmul(C2(t1, -t3), w2);
    y[3] = cmul(C2(t1, t3), w6);
    r4f(v0, v1, v2, v3, w2, w4, w6, y[4], y[5], y[6], y[7]);
}

__device__ __forceinline__ void r8i(const cplx* x, float sn, float cs, cplx* y) {
    const float r22 = 0.70710678118654752f;
    cplx w1 = C2(cs, sn);
    cplx w2 = C2(cs * cs - sn * sn, 2.f * cs * sn);
    cplx w4 = cmul(w2, w2);
    cplx w6 = cmul(w4, w2);
    cplx g0, g1, g2, g3, g4, g5, g6, g7;
    r4i(x[0], x[1], x[2], x[3], w2, w4, w6, g0, g1, g2, g3);
    r4i(x[4], x[5], x[6], x[7], w2, w4, w6, g4, g5, g6, g7);
    cplx t0 = cmul(g4, w1);
    cplx e1 = cmul(g5, w1);
    cplx e2 = cmul(g6, w1);
    cplx e3 = cmul(g7, w1);
    cplx t1 = C2(r22 * (e1.x - e1.y), r22 * (e1.x + e1.y));
    cplx t2 = C2(-e2.y, e2.x);
    cplx t3 = C2(-r22 * (e3.x + e3.y), r22 * (e3.x - e3.y));
    y[0] = g0 + t0; y[4] = g0 - t0;
    y[1] = g1 + t1; y[5] = g1 - t1;
    y[2] = g2 + t2; y[6] = g2 - t2;
    y[3] = g3 + t3; y[7] = g3 - t3;
}

// One block per (b,c) row, 512 threads — proven no-spill shape (VGPR 60).
// R1-R3: every 1024-thread variant spilled regardless of restructure. Do not
// revisit. R16: cplx packed-math rewrite + r8f_real pass A; structure,
// indices, swizzles identical to the R0/R4 verified kernel.
__global__ __launch_bounds__(512, 4) void fft_analytic_kernel(const float* __restrict__ x,
                                                              ushort* __restrict__ zc,
                                                              ushort* __restrict__ zs) {
    __shared__ __align__(16) cplx buf[T_LEN];   // 64 KiB
    const int tid = threadIdx.x;
    const int row = blockIdx.x;
    const float* xr = x + ((size_t)row << 13);

    // fwd pass Q=1024 fused with global load (x real; imag folds away)
    for (int s = 0; s < 2; ++s) {
        const int g = tid + (s << 9);
        float X[8];
        cplx Y[8];
#pragma unroll
        for (int c = 0; c < 8; ++c) X[c] = xr[g + (c << 10)];
        float sn, cs;
        __sincosf(-(float)M_PI / 4096.f * (float)g, &sn, &cs);
        r8f_real(X, sn, cs, Y);
#pragma unroll
        for (int c = 0; c < 8; ++c) buf[g + (c << 10)] = Y[c];
    }
    __syncthreads();

    // fwd LDS pass Q=128
    {
        const float astep = -(float)M_PI / 512.f;
        for (int s = 0; s < 2; ++s) {
            const int g = tid + (s << 9);
            const int j = g & 127;
            const int i = ((g & ~127) << 3) | j;
            cplx xx[8], yy[8];
#pragma unroll
            for (int c = 0; c < 8; ++c) xx[c] = buf[i + c * 128];
            float sn, cs;
            __sincosf(astep * (float)j, &sn, &cs);
            r8f(xx, sn, cs, yy);
#pragma unroll
            for (int c = 0; c < 8; ++c) buf[i + c * 128] = yy[c];
        }
        __syncthreads();
    }

    // fwd LDS pass Q=16: plain reads, swizzled writes (slot = idx ^ 2c)
    {
        const float astep = -(float)M_PI / 64.f;
        for (int s = 0; s < 2; ++s) {
            const int g = tid + (s << 9);
            const int j = g & 15;
            const int i = ((g & ~15) << 3) | j;
            cplx xx[8], yy[8];
#pragma unroll
            for (int c = 0; c < 8; ++c) xx[c] = buf[i + c * 16];
            float sn, cs;
            __sincosf(astep * (float)j, &sn, &cs);
            r8f(xx, sn, cs, yy);
#pragma unroll
            for (int c = 0; c < 8; ++c) buf[(i + c * 16) ^ (2 * c)] = yy[c];
        }
        __syncthreads();
    }

    // register-local middle: thread owns elements [16*tid, 16*tid+16).
    // Element-float4 (8*tid+p) lives at slot4 (8*tid + (p^(tid&7))).
    {
        cplx v[16];
        float4* bb = (float4*)buf;
        const int K = tid & 7;
#pragma unroll
        for (int p = 0; p < 8; ++p) {
            float4 f = bb[8 * tid + (p ^ K)];
            v[2 * p]     = C2(f.x, f.y);
            v[2 * p + 1] = C2(f.z, f.w);
        }
        cplx xe[8], xo[8], E[8], O[8], t[8];
#pragma unroll
        for (int c = 0; c < 8; ++c) { xe[c] = v[2 * c]; xo[c] = v[2 * c + 1]; }
        r8f(xe, 0.f, 1.f, E);
        r8f(xo, -SIN8, COS8, O);
#pragma unroll
        for (int c = 0; c < 8; ++c) t[c] = E[c] + O[c];   // dist-1 + mask fuse
        r8i(t, 0.f, 1.f, xe);
        r8i(t, SIN8, COS8, xo);
#pragma unroll
        for (int p = 0; p < 8; ++p)
            bb[8 * tid + (p ^ K)] = make_float4(xe[p].x, xe[p].y, xo[p].x, xo[p].y);
    }
    __syncthreads();

    // inv LDS pass Q=16: swizzled reads, plain writes
    {
        const float astep = (float)M_PI / 64.f;
        for (int s = 0; s < 2; ++s) {
            const int g = tid + (s << 9);
            const int j = g & 15;
            const int i = ((g & ~15) << 3) | j;
            cplx xx[8], yy[8];
#pragma unroll
            for (int c = 0; c < 8; ++c) xx[c] = buf[(i + c * 16) ^ (2 * c)];
            float sn, cs;
            __sincosf(astep * (float)j, &sn, &cs);
            r8i(xx, sn, cs, yy);
#pragma unroll
            for (int c = 0; c < 8; ++c) buf[i + c * 16] = yy[c];
        }
        __syncthreads();
    }

    // inv LDS pass Q=128
    {
        const float astep = (float)M_PI / 512.f;
        for (int s = 0; s < 2; ++s) {
            const int g = tid + (s << 9);
            const int j = g & 127;
            const int i = ((g & ~127) << 3) | j;
            cplx xx[8], yy[8];
#pragma unroll
            for (int c = 0; c < 8; ++c) xx[c] = buf[i + c * 128];
            float sn, cs;
            __sincosf(astep * (float)j, &sn, &cs);
            r8i(xx, sn, cs, yy);
#pragma unroll
            for (int c = 0; c < 8; ++c) buf[i + c * 128] = yy[c];
        }
        __syncthreads();
    }

    // final inv pass Q=1024 fused with normalize + contiguous row-major store
    ushort* zcr = zc + ((size_t)row << 13);
    ushort* zsr = zs + ((size_t)row << 13);
    for (int s = 0; s < 2; ++s) {
        const int g = tid + (s << 9);
        cplx xx[8], yy[8];
#pragma unroll
        for (int c = 0; c < 8; ++c) xx[c] = buf[g + (c << 10)];
        float sn, cs;
        __sincosf((float)M_PI / 4096.f * (float)g, &sn, &cs);
        r8i(xx, sn, cs, yy);
#pragma unroll
        for (int c = 0; c < 8; ++c) {
            cplx vv = yy[c];
            float n2 = vv.x * vv.x + vv.y * vv.y;
            float cc = 1.f, ss = 0.f;
            if (n2 > 0.f) { float inv = rsqrtf(n2); cc = vv.x * inv; ss = vv.y * inv; }
            zcr[g + (c << 10)] = f2bf(cc);
            zsr[g + (c << 10)] = f2bf(ss);
        }
    }
}

// MFMA Gram partials — R15 structure, byte-identical to R7 (which cut total
// by ~8 us and pushed gram out of the top-5): global_load_lds DMA staging,
// counted vmcnt(4) (never 0 in steady state), double-buffered LDS,
// pre-swizzled-global-source XOR layout (rule #21).
__global__ __launch_bounds__(512, 4) void gram_kernel(const ushort* __restrict__ zc,
                                                      const ushort* __restrict__ zs,
                                                      __half2* __restrict__ partial) {
    const int b = blockIdx.x, kc = blockIdx.y;
    const int tid = threadIdx.x;
    const int wave = tid >> 6;
    const int lane = tid & 63;
    const int wr = wave & 3, wcol = wave >> 2;
    const int lane31 = tid & 31;
    const int half = (tid >> 5) & 1;

    __shared__ __align__(16) ushort sZ[2 * BUFSZ];   // 64 KiB

    f32x16 accRe[2], accIm[2];
#pragma unroll
    for (int v = 0; v < 2; ++v)
#pragma unroll
        for (int r = 0; r < 16; ++r) { accRe[v][r] = 0.f; accIm[v][r] = 0.f; }

    const size_t base = ((size_t)b * CHN) << 13;
    const int k0 = kc << 8;   // *256 (k-chunk)

    const ushort* gsrc[4];
    int lbase[4];
#pragma unroll
    for (int q = 0; q < 4; ++q) {
        int L = (q * 8 + wave) * 64 + lane;
        int plane = L >> 10;
        int r = (L >> 3) & 127;
        int slot = L & 7;
        int c = slot ^ (r & 7);
        gsrc[q] = (plane ? zs : zc) + base + ((size_t)r << 13) + (size_t)(k0 + c * 8);
        lbase[q] = (q * 8 + wave) * 512;
    }

#define STAGE(IT, BUF) do {                                                        \
        _Pragma("unroll")                                                          \
        for (int q = 0; q < 4; ++q)                                                \
            __builtin_amdgcn_global_load_lds(                                      \
                (gld_src_t*)(gsrc[q] + (IT) * KSTAGE),                             \
                (gld_dst_t*)&sZ[(BUF) * BUFSZ + lbase[q]], 16, 0, 0);              \
    } while (0)

    STAGE(0, 0);
    STAGE(1, 1);

#pragma unroll
    for (int it = 0; it < NITER; ++it) {
        if (it < NITER - 1) { asm volatile("s_waitcnt vmcnt(4)" ::: "memory"); }
        else                { asm volatile("s_waitcnt vmcnt(0)" ::: "memory"); }
        __builtin_amdgcn_sched_barrier(0);
        __builtin_amdgcn_s_barrier();

        const ushort* S = sZ + (it & 1) * BUFSZ;
#pragma unroll
        for (int kb = 0; kb < KSTAGE; kb += 16) {
            const int cA = (kb >> 3) + half;
            const int rowA = wr * 32 + lane31;
            const int aoff = rowA * KROW + ((cA ^ (rowA & 7)) << 3);
            bf16x8 aC = *(const bf16x8*)&S[aoff];
            bf16x8 aS = *(const bf16x8*)&S[SPLANE + aoff];
            bf16x8 aCn;
#pragma unroll
            for (int r = 0; r < 8; ++r) aCn[r] = (short)(aC[r] ^ (short)0x8000);
            bf16x8 bC[2], bS[2];
#pragma unroll
            for (int v = 0; v < 2; ++v) {
                const int rowB = wcol * 64 + v * 32 + lane31;
                const int boff = rowB * KROW + ((cA ^ (rowB & 7)) << 3);
                bC[v] = *(const bf16x8*)&S[boff];
                bS[v] = *(const bf16x8*)&S[SPLANE + boff];
            }
            accRe[0] = __builtin_amdgcn_mfma_f32_32x32x16_bf16(aC,  bC[0], accRe[0], 0, 0, 0);
            accRe[1] = __builtin_amdgcn_mfma_f32_32x32x16_bf16(aC,  bC[1], accRe[1], 0, 0, 0);
            accIm[0] = __builtin_amdgcn_mfma_f32_32x32x16_bf16(aS,  bC[0], accIm[0], 0, 0, 0);
            accIm[1] = __builtin_amdgcn_mfma_f32_32x32x16_bf16(aS,  bC[1], accIm[1], 0, 0, 0);
            accRe[0] = __builtin_amdgcn_mfma_f32_32x32x16_bf16(aS,  bS[0], accRe[0], 0, 0, 0);
            accRe[1] = __builtin_amdgcn_mfma_f32_32x32x16_bf16(aS,  bS[1], accRe[1], 0, 0, 0);
            accIm[0] = __builtin_amdgcn_mfma_f32_32x32x16_bf16(aCn, bS[0], accIm[0], 0, 0, 0);
            accIm[1] = __builtin_amdgcn_mfma_f32_32x32x16_bf16(aCn, bS[1], accIm[1], 0, 0, 0);
        }

        barrier_lds_only();
        if (it + 2 < NITER) STAGE(it + 2, it & 1);
    }
#undef STAGE

    // C/D layout (verified m74/m101): col=lane&31, row=(reg&3)+8*(reg>>2)+4*(lane>>5)
    __half2* pb = partial + ((size_t)(kc * BATCH + b) << 14);
#pragma unroll
    for (int v = 0; v < 2; ++v)
#pragma unroll
        for (int r = 0; r < 16; ++r) {
            int rrow = (r & 3) + 8 * (r >> 2) + 4 * half;
            int i = wr * 32 + rrow;
            int j = wcol * 64 + v * 32 + lane31;
            pb[i * CHN + j] = __floats2half2_rn(accRe[v][r], accIm[v][r]);
        }
}

__global__ __launch_bounds__(256) void reduce_kernel(const __half2* __restrict__ partial,
                                                     float* __restrict__ out) {
    const size_t i = (size_t)blockIdx.x * 256 + threadIdx.x;
    const size_t n = (size_t)BATCH * CHN * CHN;
    if (i >= n) return;
    float re = 0.0f, im = 0.0f;
#pragma unroll
    for (int c = 0; c < NKCHUNK; ++c) {
        float2 p = __half22float2(partial[(size_t)c * n + i]);
        re += p.x;
        im += p.y;
    }
    out[i] = sqrtf(re * re + im * im) * (1.0f / (float)T_LEN);
}

extern "C" void kernel_launch(void* const* d_in, const int* in_sizes, int n_in,
                              void* d_out, int out_size, void* d_ws, size_t ws_size,
                              hipStream_t stream) {
    const float* x = (const float*)d_in[0];
    float* out = (float*)d_out;

    const size_t plane_elems = (size_t)BATCH * CHN * T_LEN;                 // 16.8M
    ushort* zc = (ushort*)d_ws;                                             // 33.55 MB
    ushort* zs = zc + plane_elems;                                          // +33.55 MB
    __half2* partial = (__half2*)((char*)d_ws + 2 * plane_elems * sizeof(ushort)); // +33.55 MB (NKCHUNK=32)

    fft_analytic_kernel<<<BATCH * CHN, 512, 0, stream>>>(x, zc, zs);

    dim3 g2(BATCH, NKCHUNK);
    gram_kernel<<<g2, 512, 0, stream>>>(zc, zs, partial);

    const int n_out = BATCH * CHN * CHN;
    reduce_kernel<<<(n_out + 255) / 256, 256, 0, stream>>>(partial, out);
}

// Round 9
// 168.480 us; speedup vs baseline: 1.1020x; 1.0223x over previous
//
#include <hip/hip_runtime.h>
#include <hip/hip_fp16.h>
#include <math.h>

#define T_LEN 8192
#define CHN 128
#define BATCH 16
#define NKCHUNK 32   // k-chunk = 256 -> grid 16x32 = 512 blocks (2 resident/CU)
#define KSTAGE 64    // k elems staged per LDS buffer
#define NITER (T_LEN / NKCHUNK / KSTAGE)   // = 4 stage iterations per block

typedef short bf16x8 __attribute__((ext_vector_type(8)));
typedef float f32x16 __attribute__((ext_vector_type(16)));

// Native-vector complex type -> packed v_pk_* fp32 codegen (R8: -3 us fft).
typedef float cplx __attribute__((ext_vector_type(2)));
__device__ __forceinline__ cplx C2(float x, float y) { cplx r; r.x = x; r.y = y; return r; }

#define SIN8 0.3826834323650898f
#define COS8 0.9238795325112868f

// R17: zc/zs K-CHUNKED layout  [b][t>>6][chan][t&63]  (was row-major
// [row][t] with 16 KiB rows). R6 counters showed gram at 934 GB/s
// effective: each block read 128 B per 16 KiB row — a strided gather
// that caps ~1 TB/s and explains R5/R6/R7 (no structure knob helped).
// With this layout one gram STAGE reads a CONTIGUOUS 16 KiB per plane.
// fft's final store stays 128 B/wave coalesced (lane -> t&63).
#define TCHUNK 8192              // ushorts per [tc] slab: 128 chan x 64 k
#define BPLANE (128 * TCHUNK)    // ushorts per batch per plane (= CHN*T_LEN)

// gram LDS geometry (R15, unchanged): UNPADDED rows + XOR swizzle.
#define KROW 64                  // ushorts per row
#define SPLANE (128 * KROW)      // 16 KiB per plane
#define BUFSZ (2 * SPLANE)       // 32 KiB per buffer (zc+zs planes)

typedef const __attribute__((address_space(1))) uint gld_src_t;
typedef __attribute__((address_space(3))) uint gld_dst_t;

__device__ __forceinline__ ushort f2bf(float f) {
    unsigned u = __float_as_uint(f);
    unsigned r = (u + 0x7fffu + ((u >> 16) & 1u)) >> 16;
    return (ushort)r;
}

__device__ __forceinline__ void barrier_lds_only() {
    asm volatile("s_waitcnt lgkmcnt(0)" ::: "memory");
    __builtin_amdgcn_s_barrier();
}

__device__ __forceinline__ cplx cmul(cplx a, cplx b) {
    cplx t = a.yy * b.yx;            // {ay*by, ay*bx}  (pk_mul)
    cplx r = a.xx * b;               // {ax*bx, ax*by}  (pk_mul)
    return C2(r.x - t.x, r.y + t.y);
}

__device__ __forceinline__ void r4f(cplx x0, cplx x1, cplx x2, cplx x3,
                                    cplx wa, cplx wb, cplx wc,
                                    cplx& y0, cplx& y1, cplx& y2, cplx& y3) {
    cplx t0 = x0 + x2, t1 = x0 - x2;
    cplx t2 = x1 + x3, t3 = x1 - x3;
    y0 = t0 + t2;
    y1 = cmul(t0 - t2, wb);
    y2 = cmul(C2(t1.x + t3.y, t1.y - t3.x), wa);
    y3 = cmul(C2(t1.x - t3.y, t1.y + t3.x), wc);
}

__device__ __forceinline__ void r4i(cplx x0, cplx x1, cplx x2, cplx x3,
                                    cplx wa, cplx wb, cplx wc,
                                    cplx& y0, cplx& y1, cplx& y2, cplx& y3) {
    cplx a1 = cmul(x1, wb);
    cplx a2 = cmul(x2, wa);
    cplx a3 = cmul(x3, wc);
    cplx u0 = x0 + a1, u1 = x0 - a1;
    cplx p = a2 + a3;
    cplx m = C2(-(a2.y - a3.y), a2.x - a3.x);
    y0 = u0 + p; y2 = u0 - p;
    y1 = u1 + m; y3 = u1 - m;
}

__device__ __forceinline__ void r8f(const cplx* x, float sn, float cs, cplx* y) {
    const float r22 = 0.70710678118654752f;
    cplx w1 = C2(cs, sn);
    cplx w2 = C2(cs * cs - sn * sn, 2.f * cs * sn);
    cplx w4 = cmul(w2, w2);
    cplx w6 = cmul(w4, w2);
    cplx u0 = x[0] + x[4], u1 = x[1] + x[5], u2 = x[2] + x[6], u3 = x[3] + x[7];
    cplx e0 = cmul(x[0] - x[4], w1);
    cplx e1 = cmul(x[1] - x[5], w1);
    cplx e2 = cmul(x[2] - x[6], w1);
    cplx e3 = cmul(x[3] - x[7], w1);
    cplx v0 = e0;
    cplx v1 = C2(r22 * (e1.x + e1.y), r22 * (e1.y - e1.x));
    cplx v2 = C2(e2.y, -e2.x);
    cplx v3 = C2(r22 * (e3.y - e3.x), -r22 * (e3.x + e3.y));
    r4f(u0, u1, u2, u3, w2, w4, w6, y[0], y[1], y[2], y[3]);
    r4f(v0, v1, v2, v3, w2, w4, w6, y[4], y[5], y[6], y[7]);
}

// Pass-A specialization: inputs pure real (imag = 0).
__device__ __forceinline__ void r8f_real(const float* x, float sn, float cs, cplx* y) {
    const float r22 = 0.70710678118654752f;
    cplx w2 = C2(cs * cs - sn * sn, 2.f * cs * sn);
    cplx w4 = cmul(w2, w2);
    cplx w6 = cmul(w4, w2);
    float u0 = x[0] + x[4], u1 = x[1] + x[5], u2 = x[2] + x[6], u3 = x[3] + x[7];
    float d0 = x[0] - x[4], d1 = x[1] - x[5], d2 = x[2] - x[6], d3 = x[3] - x[7];
    cplx e1 = C2(d1 * cs, d1 * sn);
    cplx e2 = C2(d2 * cs, d2 * sn);
    cplx e3 = C2(d3 * cs, d3 * sn);
    cplx v0 = C2(d0 * cs, d0 * sn);
    cplx v1 = C2(r22 * (e1.x + e1.y), r22 * (e1.y - e1.x));
    cplx v2 = C2(e2.y, -e2.x);
    cplx v3 = C2(r22 * (e3.y - e3.x), -r22 * (e3.x + e3.y));
    float t0 = u0 + u2, t1 = u0 - u2, t2 = u1 + u3, t3 = u1 - u3;
    y[0] = C2(t0 + t2, 0.f);
    float s1 = t0 - t2;
    y[1] = C2(s1 * w4.x, s1 * w4.y);
    y[2] = cmul(C2(t1, -t3), w2);
    y[3] = cmul(C2(t1, t3), w6);
    r4f(v0, v1, v2, v3, w2, w4, w6, y[4], y[5], y[6], y[7]);
}

__device__ __forceinline__ void r8i(const cplx* x, float sn, float cs, cplx* y) {
    const float r22 = 0.70710678118654752f;
    cplx w1 = C2(cs, sn);
    cplx w2 = C2(cs * cs - sn * sn, 2.f * cs * sn);
    cplx w4 = cmul(w2, w2);
    cplx w6 = cmul(w4, w2);
    cplx g0, g1, g2, g3, g4, g5, g6, g7;
    r4i(x[0], x[1], x[2], x[3], w2, w4, w6, g0, g1, g2, g3);
    r4i(x[4], x[5], x[6], x[7], w2, w4, w6, g4, g5, g6, g7);
    cplx t0 = cmul(g4, w1);
    cplx e1 = cmul(g5, w1);
    cplx e2 = cmul(g6, w1);
    cplx e3 = cmul(g7, w1);
    cplx t1 = C2(r22 * (e1.x - e1.y), r22 * (e1.x + e1.y));
    cplx t2 = C2(-e2.y, e2.x);
    cplx t3 = C2(-r22 * (e3.x + e3.y), r22 * (e3.x - e3.y));
    y[0] = g0 + t0; y[4] = g0 - t0;
    y[1] = g1 + t1; y[5] = g1 - t1;
    y[2] = g2 + t2; y[6] = g2 - t2;
    y[3] = g3 + t3; y[7] = g3 - t3;
}

// One block per (b,c) row, 512 threads — proven no-spill shape (VGPR 52).
// R1-R3: 1024-thread variants spill; do not revisit. R17: only the final
// store addressing changed (k-chunked zc/zs layout); all FFT math, indices,
// swizzles identical to the R8 passing kernel.
__global__ __launch_bounds__(512, 4) void fft_analytic_kernel(const float* __restrict__ x,
                                                              ushort* __restrict__ zc,
                                                              ushort* __restrict__ zs) {
    __shared__ __align__(16) cplx buf[T_LEN];   // 64 KiB
    const int tid = threadIdx.x;
    const int row = blockIdx.x;
    const float* xr = x + ((size_t)row << 13);

    // fwd pass Q=1024 fused with global load (x real; imag folds away)
    for (int s = 0; s < 2; ++s) {
        const int g = tid + (s << 9);
        float X[8];
        cplx Y[8];
#pragma unroll
        for (int c = 0; c < 8; ++c) X[c] = xr[g + (c << 10)];
        float sn, cs;
        __sincosf(-(float)M_PI / 4096.f * (float)g, &sn, &cs);
        r8f_real(X, sn, cs, Y);
#pragma unroll
        for (int c = 0; c < 8; ++c) buf[g + (c << 10)] = Y[c];
    }
    __syncthreads();

    // fwd LDS pass Q=128
    {
        const float astep = -(float)M_PI / 512.f;
        for (int s = 0; s < 2; ++s) {
            const int g = tid + (s << 9);
            const int j = g & 127;
            const int i = ((g & ~127) << 3) | j;
            cplx xx[8], yy[8];
#pragma unroll
            for (int c = 0; c < 8; ++c) xx[c] = buf[i + c * 128];
            float sn, cs;
            __sincosf(astep * (float)j, &sn, &cs);
            r8f(xx, sn, cs, yy);
#pragma unroll
            for (int c = 0; c < 8; ++c) buf[i + c * 128] = yy[c];
        }
        __syncthreads();
    }

    // fwd LDS pass Q=16: plain reads, swizzled writes (slot = idx ^ 2c)
    {
        const float astep = -(float)M_PI / 64.f;
        for (int s = 0; s < 2; ++s) {
            const int g = tid + (s << 9);
            const int j = g & 15;
            const int i = ((g & ~15) << 3) | j;
            cplx xx[8], yy[8];
#pragma unroll
            for (int c = 0; c < 8; ++c) xx[c] = buf[i + c * 16];
            float sn, cs;
            __sincosf(astep * (float)j, &sn, &cs);
            r8f(xx, sn, cs, yy);
#pragma unroll
            for (int c = 0; c < 8; ++c) buf[(i + c * 16) ^ (2 * c)] = yy[c];
        }
        __syncthreads();
    }

    // register-local middle: thread owns elements [16*tid, 16*tid+16).
    {
        cplx v[16];
        float4* bb = (float4*)buf;
        const int K = tid & 7;
#pragma unroll
        for (int p = 0; p < 8; ++p) {
            float4 f = bb[8 * tid + (p ^ K)];
            v[2 * p]     = C2(f.x, f.y);
            v[2 * p + 1] = C2(f.z, f.w);
        }
        cplx xe[8], xo[8], E[8], O[8], t[8];
#pragma unroll
        for (int c = 0; c < 8; ++c) { xe[c] = v[2 * c]; xo[c] = v[2 * c + 1]; }
        r8f(xe, 0.f, 1.f, E);
        r8f(xo, -SIN8, COS8, O);
#pragma unroll
        for (int c = 0; c < 8; ++c) t[c] = E[c] + O[c];   // dist-1 + mask fuse
        r8i(t, 0.f, 1.f, xe);
        r8i(t, SIN8, COS8, xo);
#pragma unroll
        for (int p = 0; p < 8; ++p)
            bb[8 * tid + (p ^ K)] = make_float4(xe[p].x, xe[p].y, xo[p].x, xo[p].y);
    }
    __syncthreads();

    // inv LDS pass Q=16: swizzled reads, plain writes
    {
        const float astep = (float)M_PI / 64.f;
        for (int s = 0; s < 2; ++s) {
            const int g = tid + (s << 9);
            const int j = g & 15;
            const int i = ((g & ~15) << 3) | j;
            cplx xx[8], yy[8];
#pragma unroll
            for (int c = 0; c < 8; ++c) xx[c] = buf[(i + c * 16) ^ (2 * c)];
            float sn, cs;
            __sincosf(astep * (float)j, &sn, &cs);
            r8i(xx, sn, cs, yy);
#pragma unroll
            for (int c = 0; c < 8; ++c) buf[i + c * 16] = yy[c];
        }
        __syncthreads();
    }

    // inv LDS pass Q=128
    {
        const float astep = (float)M_PI / 512.f;
        for (int s = 0; s < 2; ++s) {
            const int g = tid + (s << 9);
            const int j = g & 127;
            const int i = ((g & ~127) << 3) | j;
            cplx xx[8], yy[8];
#pragma unroll
            for (int c = 0; c < 8; ++c) xx[c] = buf[i + c * 128];
            float sn, cs;
            __sincosf(astep * (float)j, &sn, &cs);
            r8i(xx, sn, cs, yy);
#pragma unroll
            for (int c = 0; c < 8; ++c) buf[i + c * 128] = yy[c];
        }
        __syncthreads();
    }

    // final inv pass Q=1024 fused with normalize + K-CHUNKED store:
    // element t -> plane[b][t>>6][chan][t&63]. Lanes are consecutive in
    // (t&63) -> 128 B/wave coalesced, same as the old row-major store.
    {
        const size_t base = ((size_t)(row >> 7) * BPLANE) + (size_t)(row & 127) * 64;
        ushort* zcr = zc + base;
        ushort* zsr = zs + base;
        const int tk = tid & 63;
        const int tcb = tid >> 6;   // t>>6 contribution from tid (0..7)
        for (int s = 0; s < 2; ++s) {
            const int g = tid + (s << 9);
            cplx xx[8], yy[8];
#pragma unroll
            for (int c = 0; c < 8; ++c) xx[c] = buf[g + (c << 10)];
            float sn, cs;
            __sincosf((float)M_PI / 4096.f * (float)g, &sn, &cs);
            r8i(xx, sn, cs, yy);
#pragma unroll
            for (int c = 0; c < 8; ++c) {
                cplx vv = yy[c];
                float n2 = vv.x * vv.x + vv.y * vv.y;
                float cc = 1.f, ss = 0.f;
                if (n2 > 0.f) { float inv = rsqrtf(n2); cc = vv.x * inv; ss = vv.y * inv; }
                const int tc = tcb + s * 8 + c * 16;          // t>>6
                zcr[(size_t)tc * TCHUNK + tk] = f2bf(cc);
                zsr[(size_t)tc * TCHUNK + tk] = f2bf(ss);
            }
        }
    }
}

// MFMA Gram partials — R15 DMA/vmcnt structure + R17 contiguous layout.
// Each STAGE now reads a fully contiguous 16 KiB per plane (rows adjacent
// in memory); the XOR pre-swizzle only permutes lanes within the same
// contiguous 1 KiB wave-span, so coalescing is preserved (rule #21 layout:
// LDS slot(r,s) holds global chunk c = s^(r&7); MFMA reads apply the XOR).
__global__ __launch_bounds__(512, 4) void gram_kernel(const ushort* __restrict__ zc,
                                                      const ushort* __restrict__ zs,
                                                      __half2* __restrict__ partial) {
    const int b = blockIdx.x, kc = blockIdx.y;
    const int tid = threadIdx.x;
    const int wave = tid >> 6;
    const int lane = tid & 63;
    const int wr = wave & 3, wcol = wave >> 2;
    const int lane31 = tid & 31;
    const int half = (tid >> 5) & 1;

    __shared__ __align__(16) ushort sZ[2 * BUFSZ];   // 64 KiB

    f32x16 accRe[2], accIm[2];
#pragma unroll
    for (int v = 0; v < 2; ++v)
#pragma unroll
        for (int r = 0; r < 16; ++r) { accRe[v][r] = 0.f; accIm[v][r] = 0.f; }

    // k-chunk kc covers tc slabs [kc*NITER, kc*NITER+NITER).
    const size_t base = (size_t)b * BPLANE + (size_t)(kc * NITER) * TCHUNK;

    const ushort* gsrc[4];
    int lbase[4];
#pragma unroll
    for (int q = 0; q < 4; ++q) {
        int L = (q * 8 + wave) * 64 + lane;   // linear 16B-chunk id in buffer
        int plane = L >> 10;
        int r = (L >> 3) & 127;
        int slot = L & 7;
        int c = slot ^ (r & 7);
        gsrc[q] = (plane ? zs : zc) + base + (size_t)r * 64 + (size_t)c * 8;
        lbase[q] = (q * 8 + wave) * 512;
    }

#define STAGE(IT, BUF) do {                                                        \
        _Pragma("unroll")                                                          \
        for (int q = 0; q < 4; ++q)                                                \
            __builtin_amdgcn_global_load_lds(                                      \
                (gld_src_t*)(gsrc[q] + (size_t)(IT) * TCHUNK),                     \
                (gld_dst_t*)&sZ[(BUF) * BUFSZ + lbase[q]], 16, 0, 0);              \
    } while (0)

    STAGE(0, 0);
    STAGE(1, 1);

#pragma unroll
    for (int it = 0; it < NITER; ++it) {
        if (it < NITER - 1) { asm volatile("s_waitcnt vmcnt(4)" ::: "memory"); }
        else                { asm volatile("s_waitcnt vmcnt(0)" ::: "memory"); }
        __builtin_amdgcn_sched_barrier(0);
        __builtin_amdgcn_s_barrier();

        const ushort* S = sZ + (it & 1) * BUFSZ;
#pragma unroll
        for (int kb = 0; kb < KSTAGE; kb += 16) {
            const int cA = (kb >> 3) + half;
            const int rowA = wr * 32 + lane31;
            const int aoff = rowA * KROW + ((cA ^ (rowA & 7)) << 3);
            bf16x8 aC = *(const bf16x8*)&S[aoff];
            bf16x8 aS = *(const bf16x8*)&S[SPLANE + aoff];
            bf16x8 aCn;
#pragma unroll
            for (int r = 0; r < 8; ++r) aCn[r] = (short)(aC[r] ^ (short)0x8000);
            bf16x8 bC[2], bS[2];
#pragma unroll
            for (int v = 0; v < 2; ++v) {
                const int rowB = wcol * 64 + v * 32 + lane31;
                const int boff = rowB * KROW + ((cA ^ (rowB & 7)) << 3);
                bC[v] = *(const bf16x8*)&S[boff];
                bS[v] = *(const bf16x8*)&S[SPLANE + boff];
            }
            accRe[0] = __builtin_amdgcn_mfma_f32_32x32x16_bf16(aC,  bC[0], accRe[0], 0, 0, 0);
            accRe[1] = __builtin_amdgcn_mfma_f32_32x32x16_bf16(aC,  bC[1], accRe[1], 0, 0, 0);
            accIm[0] = __builtin_amdgcn_mfma_f32_32x32x16_bf16(aS,  bC[0], accIm[0], 0, 0, 0);
            accIm[1] = __builtin_amdgcn_mfma_f32_32x32x16_bf16(aS,  bC[1], accIm[1], 0, 0, 0);
            accRe[0] = __builtin_amdgcn_mfma_f32_32x32x16_bf16(aS,  bS[0], accRe[0], 0, 0, 0);
            accRe[1] = __builtin_amdgcn_mfma_f32_32x32x16_bf16(aS,  bS[1], accRe[1], 0, 0, 0);
            accIm[0] = __builtin_amdgcn_mfma_f32_32x32x16_bf16(aCn, bS[0], accIm[0], 0, 0, 0);
            accIm[1] = __builtin_amdgcn_mfma_f32_32x32x16_bf16(aCn, bS[1], accIm[1], 0, 0, 0);
        }

        barrier_lds_only();
        if (it + 2 < NITER) STAGE(it + 2, it & 1);
    }
#undef STAGE

    // C/D layout (verified m74/m101): col=lane&31, row=(reg&3)+8*(reg>>2)+4*(lane>>5)
    __half2* pb = partial + ((size_t)(kc * BATCH + b) << 14);
#pragma unroll
    for (int v = 0; v < 2; ++v)
#pragma unroll
        for (int r = 0; r < 16; ++r) {
            int rrow = (r & 3) + 8 * (r >> 2) + 4 * half;
            int i = wr * 32 + rrow;
            int j = wcol * 64 + v * 32 + lane31;
            pb[i * CHN + j] = __floats2half2_rn(accRe[v][r], accIm[v][r]);
        }
}

__global__ __launch_bounds__(256) void reduce_kernel(const __half2* __restrict__ partial,
                                                     float* __restrict__ out) {
    const size_t i = (size_t)blockIdx.x * 256 + threadIdx.x;
    const size_t n = (size_t)BATCH * CHN * CHN;
    if (i >= n) return;
    float re = 0.0f, im = 0.0f;
#pragma unroll
    for (int c = 0; c < NKCHUNK; ++c) {
        float2 p = __half22float2(partial[(size_t)c * n + i]);
        re += p.x;
        im += p.y;
    }
    out[i] = sqrtf(re * re + im * im) * (1.0f / (float)T_LEN);
}

extern "C" void kernel_launch(void* const* d_in, const int* in_sizes, int n_in,
                              void* d_out, int out_size, void* d_ws, size_t ws_size,
                              hipStream_t stream) {
    const float* x = (const float*)d_in[0];
    float* out = (float*)d_out;

    const size_t plane_elems = (size_t)BATCH * CHN * T_LEN;                 // 16.8M
    ushort* zc = (ushort*)d_ws;                                             // 33.55 MB
    ushort* zs = zc + plane_elems;                                          // +33.55 MB
    __half2* partial = (__half2*)((char*)d_ws + 2 * plane_elems * sizeof(ushort)); // +33.55 MB (NKCHUNK=32)

    fft_analytic_kernel<<<BATCH * CHN, 512, 0, stream>>>(x, zc, zs);

    dim3 g2(BATCH, NKCHUNK);
    gram_kernel<<<g2, 512, 0, stream>>>(zc, zs, partial);

    const int n_out = BATCH * CHN * CHN;
    reduce_kernel<<<(n_out + 255) / 256, 256, 0, stream>>>(partial, out);
}

// Round 10
// 162.356 us; speedup vs baseline: 1.1436x; 1.0377x over previous
//
#include <hip/hip_runtime.h>
#include <hip/hip_fp16.h>
#include <math.h>

#define T_LEN 8192
#define CHN 128
#define BATCH 16
#define NKCHUNK 32   // k-chunk = 256 -> grid 16x32 = 512 blocks
#define KSTAGE 32    // R18: k elems per LDS stage (was 64) -> NITER 8, depth-3 pipeline
#define NITER (T_LEN / NKCHUNK / KSTAGE)   // = 8 stage iterations per block

typedef short bf16x8 __attribute__((ext_vector_type(8)));
typedef float f32x16 __attribute__((ext_vector_type(16)));

// Native-vector complex type -> packed v_pk_* fp32 codegen (R8: -3 us fft).
typedef float cplx __attribute__((ext_vector_type(2)));
__device__ __forceinline__ cplx C2(float x, float y) { cplx r; r.x = x; r.y = y; return r; }

#define SIN8 0.3826834323650898f
#define COS8 0.9238795325112868f

// zc/zs K-CHUNKED layout [b][t>>6][chan][t&63] (R17: contiguous gram reads).
#define TCHUNK 8192              // ushorts per [tc] slab: 128 chan x 64 k
#define BPLANE (128 * TCHUNK)    // ushorts per batch per plane (= CHN*T_LEN)

// R18 gram LDS geometry: KSTAGE=32 -> plane = 128 rows x 32 k = 8 KiB.
// Column-major swizzle: chunk (r,c) [c=0..3, 16B] stored at plane-group
// offset (c^(r&3))*256B + (r&15)*16B within the (r>>4) 1-KiB group.
// Read of fixed chunk cA across rows: bank_start = 4*(r&7) — IDENTICAL
// bank pattern to the padded SROW=72 layout that measured
// SQ_LDS_BANK_CONFLICT = 0 (R6 gram dispatch). Staging keeps LDS dest
// linear (m104) by permuting the per-lane GLOBAL source (rule #21).
#define GSP 4096                 // ushorts per plane (8 KiB)
#define GBUF (2 * GSP)           // ushorts per buffer (zc+zs planes, 16 KiB)

typedef const __attribute__((address_space(1))) uint gld_src_t;
typedef __attribute__((address_space(3))) uint gld_dst_t;

__device__ __forceinline__ ushort f2bf(float f) {
    unsigned u = __float_as_uint(f);
    unsigned r = (u + 0x7fffu + ((u >> 16) & 1u)) >> 16;
    return (ushort)r;
}

__device__ __forceinline__ void barrier_lds_only() {
    asm volatile("s_waitcnt lgkmcnt(0)" ::: "memory");
    __builtin_amdgcn_s_barrier();
}

__device__ __forceinline__ cplx cmul(cplx a, cplx b) {
    cplx t = a.yy * b.yx;            // {ay*by, ay*bx}  (pk_mul)
    cplx r = a.xx * b;               // {ax*bx, ax*by}  (pk_mul)
    return C2(r.x - t.x, r.y + t.y);
}

// R18: hoisted twiddle chain. Passes B/C/D/E share one sincos per pass
// (512 = 0 mod 128 and mod 16, so j is s-invariant), and D/E/F are exact
// conjugates of C/B/A. 4 sincos pairs + 4 chains per thread replace 12/14.
struct Tw { cplx w1, w2, w4, w6; };

__device__ __forceinline__ Tw mkchain(float sn, float cs) {
    Tw t;
    t.w1 = C2(cs, sn);
    t.w2 = C2(cs * cs - sn * sn, 2.f * cs * sn);
    t.w4 = cmul(t.w2, t.w2);
    t.w6 = cmul(t.w4, t.w2);
    return t;
}

__device__ __forceinline__ Tw tconj(Tw t) {
    t.w1.y = -t.w1.y; t.w2.y = -t.w2.y; t.w4.y = -t.w4.y; t.w6.y = -t.w6.y;
    return t;
}

__device__ __forceinline__ void r4f(cplx x0, cplx x1, cplx x2, cplx x3,
                                    cplx wa, cplx wb, cplx wc,
                                    cplx& y0, cplx& y1, cplx& y2, cplx& y3) {
    cplx t0 = x0 + x2, t1 = x0 - x2;
    cplx t2 = x1 + x3, t3 = x1 - x3;
    y0 = t0 + t2;
    y1 = cmul(t0 - t2, wb);
    y2 = cmul(C2(t1.x + t3.y, t1.y - t3.x), wa);
    y3 = cmul(C2(t1.x - t3.y, t1.y + t3.x), wc);
}

__device__ __forceinline__ void r4i(cplx x0, cplx x1, cplx x2, cplx x3,
                                    cplx wa, cplx wb, cplx wc,
                                    cplx& y0, cplx& y1, cplx& y2, cplx& y3) {
    cplx a1 = cmul(x1, wb);
    cplx a2 = cmul(x2, wa);
    cplx a3 = cmul(x3, wc);
    cplx u0 = x0 + a1, u1 = x0 - a1;
    cplx p = a2 + a3;
    cplx m = C2(-(a2.y - a3.y), a2.x - a3.x);
    y0 = u0 + p; y2 = u0 - p;
    y1 = u1 + m; y3 = u1 - m;
}

__device__ __forceinline__ void r8f(const cplx* x, const Tw& W, cplx* y) {
    const float r22 = 0.70710678118654752f;
    cplx u0 = x[0] + x[4], u1 = x[1] + x[5], u2 = x[2] + x[6], u3 = x[3] + x[7];
    cplx e0 = cmul(x[0] - x[4], W.w1);
    cplx e1 = cmul(x[1] - x[5], W.w1);
    cplx e2 = cmul(x[2] - x[6], W.w1);
    cplx e3 = cmul(x[3] - x[7], W.w1);
    cplx v0 = e0;
    cplx v1 = C2(r22 * (e1.x + e1.y), r22 * (e1.y - e1.x));
    cplx v2 = C2(e2.y, -e2.x);
    cplx v3 = C2(r22 * (e3.y - e3.x), -r22 * (e3.x + e3.y));
    r4f(u0, u1, u2, u3, W.w2, W.w4, W.w6, y[0], y[1], y[2], y[3]);
    r4f(v0, v1, v2, v3, W.w2, W.w4, W.w6, y[4], y[5], y[6], y[7]);
}

// Pass-A specialization: inputs pure real (imag = 0).
__device__ __forceinline__ void r8f_real(const float* x, const Tw& W, cplx* y) {
    const float r22 = 0.70710678118654752f;
    const float cs = W.w1.x, sn = W.w1.y;
    float u0 = x[0] + x[4], u1 = x[1] + x[5], u2 = x[2] + x[6], u3 = x[3] + x[7];
    float d0 = x[0] - x[4], d1 = x[1] - x[5], d2 = x[2] - x[6], d3 = x[3] - x[7];
    cplx e1 = C2(d1 * cs, d1 * sn);
    cplx e2 = C2(d2 * cs, d2 * sn);
    cplx e3 = C2(d3 * cs, d3 * sn);
    cplx v0 = C2(d0 * cs, d0 * sn);
    cplx v1 = C2(r22 * (e1.x + e1.y), r22 * (e1.y - e1.x));
    cplx v2 = C2(e2.y, -e2.x);
    cplx v3 = C2(r22 * (e3.y - e3.x), -r22 * (e3.x + e3.y));
    float t0 = u0 + u2, t1 = u0 - u2, t2 = u1 + u3, t3 = u1 - u3;
    y[0] = C2(t0 + t2, 0.f);
    float s1 = t0 - t2;
    y[1] = C2(s1 * W.w4.x, s1 * W.w4.y);
    y[2] = cmul(C2(t1, -t3), W.w2);
    y[3] = cmul(C2(t1, t3), W.w6);
    r4f(v0, v1, v2, v3, W.w2, W.w4, W.w6, y[4], y[5], y[6], y[7]);
}

__device__ __forceinline__ void r8i(const cplx* x, const Tw& W, cplx* y) {
    const float r22 = 0.70710678118654752f;
    cplx g0, g1, g2, g3, g4, g5, g6, g7;
    r4i(x[0], x[1], x[2], x[3], W.w2, W.w4, W.w6, g0, g1, g2, g3);
    r4i(x[4], x[5], x[6], x[7], W.w2, W.w4, W.w6, g4, g5, g6, g7);
    cplx t0 = cmul(g4, W.w1);
    cplx e1 = cmul(g5, W.w1);
    cplx e2 = cmul(g6, W.w1);
    cplx e3 = cmul(g7, W.w1);
    cplx t1 = C2(r22 * (e1.x - e1.y), r22 * (e1.x + e1.y));
    cplx t2 = C2(-e2.y, e2.x);
    cplx t3 = C2(-r22 * (e3.x + e3.y), r22 * (e3.x - e3.y));
    y[0] = g0 + t0; y[4] = g0 - t0;
    y[1] = g1 + t1; y[5] = g1 - t1;
    y[2] = g2 + t2; y[6] = g2 - t2;
    y[3] = g3 + t3; y[7] = g3 - t3;
}

// One block per (b,c) row, 512 threads — proven no-spill shape.
// R1-R3: 1024-thread variants spill; do not revisit. R18: twiddles hoisted
// (4 sincos + 4 chains at entry, conjugated for inverse passes). ~32 extra
// VGPR live whole-kernel; budget is 128 (launch_bounds 512,4) and occupancy
// is LDS-limited at 2 blocks/CU, so VGPR growth to ~100 costs nothing.
__global__ __launch_bounds__(512, 4) void fft_analytic_kernel(const float* __restrict__ x,
                                                              ushort* __restrict__ zc,
                                                              ushort* __restrict__ zs) {
    __shared__ __align__(16) cplx buf[T_LEN];   // 64 KiB
    const int tid = threadIdx.x;
    const int row = blockIdx.x;
    const float* xr = x + ((size_t)row << 13);

    // hoisted twiddles (forward-sign); inverse passes use conjugates
    float snA0, csA0, snA1, csA1, snB, csB, snC, csC;
    __sincosf(-(float)M_PI / 4096.f * (float)tid, &snA0, &csA0);
    __sincosf(-(float)M_PI / 4096.f * (float)(tid + 512), &snA1, &csA1);
    __sincosf(-(float)M_PI / 512.f * (float)(tid & 127), &snB, &csB);
    __sincosf(-(float)M_PI / 64.f * (float)(tid & 15), &snC, &csC);
    const Tw wA0 = mkchain(snA0, csA0);
    const Tw wA1 = mkchain(snA1, csA1);
    const Tw wB = mkchain(snB, csB);
    const Tw wC = mkchain(snC, csC);

    // pass A: fwd radix-8 stride 1024, fused with global load (x real)
#pragma unroll
    for (int s = 0; s < 2; ++s) {
        const int g = tid + (s << 9);
        const Tw& W = s ? wA1 : wA0;
        float X[8];
        cplx Y[8];
#pragma unroll
        for (int c = 0; c < 8; ++c) X[c] = xr[g + (c << 10)];
        r8f_real(X, W, Y);
#pragma unroll
        for (int c = 0; c < 8; ++c) buf[g + (c << 10)] = Y[c];
    }
    __syncthreads();

    // pass B: fwd radix-8 stride 128 (j = g&127 is s-invariant -> one chain)
    {
#pragma unroll
        for (int s = 0; s < 2; ++s) {
            const int g = tid + (s << 9);
            const int j = g & 127;
            const int i = ((g & ~127) << 3) | j;
            cplx xx[8], yy[8];
#pragma unroll
            for (int c = 0; c < 8; ++c) xx[c] = buf[i + c * 128];
            r8f(xx, wB, yy);
#pragma unroll
            for (int c = 0; c < 8; ++c) buf[i + c * 128] = yy[c];
        }
        __syncthreads();
    }

    // pass C: fwd radix-8 stride 16: plain reads, swizzled writes (^2c)
    {
#pragma unroll
        for (int s = 0; s < 2; ++s) {
            const int g = tid + (s << 9);
            const int j = g & 15;
            const int i = ((g & ~15) << 3) | j;
            cplx xx[8], yy[8];
#pragma unroll
            for (int c = 0; c < 8; ++c) xx[c] = buf[i + c * 16];
            r8f(xx, wC, yy);
#pragma unroll
            for (int c = 0; c < 8; ++c) buf[(i + c * 16) ^ (2 * c)] = yy[c];
        }
        __syncthreads();
    }

    // register-local middle: thread owns elements [16*tid, 16*tid+16).
    {
        cplx v[16];
        float4* bb = (float4*)buf;
        const int K = tid & 7;
#pragma unroll
        for (int p = 0; p < 8; ++p) {
            float4 f = bb[8 * tid + (p ^ K)];
            v[2 * p]     = C2(f.x, f.y);
            v[2 * p + 1] = C2(f.z, f.w);
        }
        cplx xe[8], xo[8], E[8], O[8], t[8];
#pragma unroll
        for (int c = 0; c < 8; ++c) { xe[c] = v[2 * c]; xo[c] = v[2 * c + 1]; }
        r8f(xe, mkchain(0.f, 1.f), E);
        r8f(xo, mkchain(-SIN8, COS8), O);
#pragma unroll
        for (int c = 0; c < 8; ++c) t[c] = E[c] + O[c];   // dist-1 + mask fuse
        r8i(t, mkchain(0.f, 1.f), xe);
        r8i(t, mkchain(SIN8, COS8), xo);
#pragma unroll
        for (int p = 0; p < 8; ++p)
            bb[8 * tid + (p ^ K)] = make_float4(xe[p].x, xe[p].y, xo[p].x, xo[p].y);
    }
    __syncthreads();

    // pass D: inv radix-8 stride 16 (conjugate of C's chain)
    {
        const Tw wCc = tconj(wC);
#pragma unroll
        for (int s = 0; s < 2; ++s) {
            const int g = tid + (s << 9);
            const int j = g & 15;
            const int i = ((g & ~15) << 3) | j;
            cplx xx[8], yy[8];
#pragma unroll
            for (int c = 0; c < 8; ++c) xx[c] = buf[(i + c * 16) ^ (2 * c)];
            r8i(xx, wCc, yy);
#pragma unroll
            for (int c = 0; c < 8; ++c) buf[i + c * 16] = yy[c];
        }
        __syncthreads();
    }

    // pass E: inv radix-8 stride 128 (conjugate of B's chain)
    {
        const Tw wBc = tconj(wB);
#pragma unroll
        for (int s = 0; s < 2; ++s) {
            const int g = tid + (s << 9);
            const int j = g & 127;
            const int i = ((g & ~127) << 3) | j;
            cplx xx[8], yy[8];
#pragma unroll
            for (int c = 0; c < 8; ++c) xx[c] = buf[i + c * 128];
            r8i(xx, wBc, yy);
#pragma unroll
            for (int c = 0; c < 8; ++c) buf[i + c * 128] = yy[c];
        }
        __syncthreads();
    }

    // pass F: inv radix-8 stride 1024 (conjugate of A) + normalize +
    // K-CHUNKED store: element t -> plane[b][t>>6][chan][t&63].
    {
        const size_t base = ((size_t)(row >> 7) * BPLANE) + (size_t)(row & 127) * 64;
        ushort* zcr = zc + base;
        ushort* zsr = zs + base;
        const int tk = tid & 63;
        const int tcb = tid >> 6;
#pragma unroll
        for (int s = 0; s < 2; ++s) {
            const int g = tid + (s << 9);
            const Tw Wc = tconj(s ? wA1 : wA0);
            cplx xx[8], yy[8];
#pragma unroll
            for (int c = 0; c < 8; ++c) xx[c] = buf[g + (c << 10)];
            r8i(xx, Wc, yy);
#pragma unroll
            for (int c = 0; c < 8; ++c) {
                cplx vv = yy[c];
                float n2 = vv.x * vv.x + vv.y * vv.y;
                float cc = 1.f, ss = 0.f;
                if (n2 > 0.f) { float inv = rsqrtf(n2); cc = vv.x * inv; ss = vv.y * inv; }
                const int tc = tcb + s * 8 + c * 16;          // t>>6
                zcr[(size_t)tc * TCHUNK + tk] = f2bf(cc);
                zsr[(size_t)tc * TCHUNK + tk] = f2bf(ss);
            }
        }
    }
}

// MFMA Gram partials — R18: depth-3 DMA pipeline. Residual-ledger evidence
// (R6 107 / R7 99.5 / R9 93.5 us): gram's inner-loop changes moved little;
// with NITER=4 the 2-stage prologue was HALF of all stages and the block's
// life was its first vmcnt wait. Now: KSTAGE=32, NITER=8, THREE 16-KiB
// buffers (48 KiB LDS -> up to 3 blocks/CU), counted vmcnt(4)->(2)->(0)
// tail only. LDS column-major swizzle (see GSP comment) has the same read
// bank pattern as the measured-0-conflict padded layout.
__global__ __launch_bounds__(512, 4) void gram_kernel(const ushort* __restrict__ zc,
                                                      const ushort* __restrict__ zs,
                                                      __half2* __restrict__ partial) {
    const int b = blockIdx.x, kc = blockIdx.y;
    const int tid = threadIdx.x;
    const int wave = tid >> 6;
    const int lane = tid & 63;
    const int wr = wave & 3, wcol = wave >> 2;
    const int lane31 = tid & 31;
    const int half = (tid >> 5) & 1;

    __shared__ __align__(16) ushort sZ[3 * GBUF];   // 48 KiB

    f32x16 accRe[2], accIm[2];
#pragma unroll
    for (int v = 0; v < 2; ++v)
#pragma unroll
        for (int r = 0; r < 16; ++r) { accRe[v][r] = 0.f; accIm[v][r] = 0.f; }

    // kc covers 4 global t-slabs; stage it covers half-slab (it&1) of slab (it>>1).
    const size_t base = (size_t)b * BPLANE + (size_t)kc * 4 * TCHUNK;

    // Staging decode (2 x 16B chunks per thread per stage): linear chunk id
    // L -> LDS slot; data for slot s of group g: row r = g*16 + (s&15),
    // global chunk c = (s>>4) ^ (r&3)  (column-major swizzle involution).
    const ushort* gsrc[2];
    int lbase[2];
#pragma unroll
    for (int q = 0; q < 2; ++q) {
        int L = (q * 8 + wave) * 64 + lane;   // 0..1023
        int plane = L >> 9;
        int P = L & 511;
        int g = P >> 6;
        int s = P & 63;
        int r = g * 16 + (s & 15);
        int c = (s >> 4) ^ (r & 3);
        gsrc[q] = (plane ? zs : zc) + base + (size_t)r * 64 + (size_t)c * 8;
        lbase[q] = (q * 8 + wave) * 512;
    }

#define STAGE(IT, BUF) do {                                                        \
        _Pragma("unroll")                                                          \
        for (int q = 0; q < 2; ++q)                                                \
            __builtin_amdgcn_global_load_lds(                                      \
                (gld_src_t*)(gsrc[q] + (size_t)((IT) >> 1) * TCHUNK                \
                                     + (size_t)((IT) & 1) * 32),                   \
                (gld_dst_t*)&sZ[(BUF) * GBUF + lbase[q]], 16, 0, 0);               \
    } while (0)

    STAGE(0, 0);
    STAGE(1, 1);
    STAGE(2, 2);

#pragma unroll
    for (int it = 0; it < NITER; ++it) {
        // counted vmcnt: retire only the oldest stage (2 loads); up to 2
        // newer stages (4 loads) stay in flight across the barrier.
        if (it <= NITER - 3)      { asm volatile("s_waitcnt vmcnt(4)" ::: "memory"); }
        else if (it == NITER - 2) { asm volatile("s_waitcnt vmcnt(2)" ::: "memory"); }
        else                      { asm volatile("s_waitcnt vmcnt(0)" ::: "memory"); }
        __builtin_amdgcn_sched_barrier(0);
        __builtin_amdgcn_s_barrier();

        const ushort* S = sZ + (it % 3) * GBUF;
#pragma unroll
        for (int kb = 0; kb < KSTAGE; kb += 16) {
            const int cA = (kb >> 3) + half;                   // chunk 0..3
            const int rowA = wr * 32 + lane31;
            const int aoff = ((rowA >> 4) << 9) + ((cA ^ (rowA & 3)) << 7) + ((rowA & 15) << 3);
            bf16x8 aC = *(const bf16x8*)&S[aoff];
            bf16x8 aS = *(const bf16x8*)&S[GSP + aoff];
            bf16x8 aCn;
#pragma unroll
            for (int r = 0; r < 8; ++r) aCn[r] = (short)(aC[r] ^ (short)0x8000);
            bf16x8 bC[2], bS[2];
#pragma unroll
            for (int v = 0; v < 2; ++v) {
                const int rowB = wcol * 64 + v * 32 + lane31;
                const int boff = ((rowB >> 4) << 9) + ((cA ^ (rowB & 3)) << 7) + ((rowB & 15) << 3);
                bC[v] = *(const bf16x8*)&S[boff];
                bS[v] = *(const bf16x8*)&S[GSP + boff];
            }
            accRe[0] = __builtin_amdgcn_mfma_f32_32x32x16_bf16(aC,  bC[0], accRe[0], 0, 0, 0);
            accRe[1] = __builtin_amdgcn_mfma_f32_32x32x16_bf16(aC,  bC[1], accRe[1], 0, 0, 0);
            accIm[0] = __builtin_amdgcn_mfma_f32_32x32x16_bf16(aS,  bC[0], accIm[0], 0, 0, 0);
            accIm[1] = __builtin_amdgcn_mfma_f32_32x32x16_bf16(aS,  bC[1], accIm[1], 0, 0, 0);
            accRe[0] = __builtin_amdgcn_mfma_f32_32x32x16_bf16(aS,  bS[0], accRe[0], 0, 0, 0);
            accRe[1] = __builtin_amdgcn_mfma_f32_32x32x16_bf16(aS,  bS[1], accRe[1], 0, 0, 0);
            accIm[0] = __builtin_amdgcn_mfma_f32_32x32x16_bf16(aCn, bS[0], accIm[0], 0, 0, 0);
            accIm[1] = __builtin_amdgcn_mfma_f32_32x32x16_bf16(aCn, bS[1], accIm[1], 0, 0, 0);
        }

        barrier_lds_only();
        if (it + 3 < NITER) STAGE(it + 3, it % 3);
    }
#undef STAGE

    // C/D layout (verified m74/m101): col=lane&31, row=(reg&3)+8*(reg>>2)+4*(lane>>5)
    __half2* pb = partial + ((size_t)(kc * BATCH + b) << 14);
#pragma unroll
    for (int v = 0; v < 2; ++v)
#pragma unroll
        for (int r = 0; r < 16; ++r) {
            int rrow = (r & 3) + 8 * (r >> 2) + 4 * half;
            int i = wr * 32 + rrow;
            int j = wcol * 64 + v * 32 + lane31;
            pb[i * CHN + j] = __floats2half2_rn(accRe[v][r], accIm[v][r]);
        }
}

__global__ __launch_bounds__(256) void reduce_kernel(const __half2* __restrict__ partial,
                                                     float* __restrict__ out) {
    const size_t i = (size_t)blockIdx.x * 256 + threadIdx.x;
    const size_t n = (size_t)BATCH * CHN * CHN;
    if (i >= n) return;
    float re = 0.0f, im = 0.0f;
#pragma unroll
    for (int c = 0; c < NKCHUNK; ++c) {
        float2 p = __half22float2(partial[(size_t)c * n + i]);
        re += p.x;
        im += p.y;
    }
    out[i] = sqrtf(re * re + im * im) * (1.0f / (float)T_LEN);
}

extern "C" void kernel_launch(void* const* d_in, const int* in_sizes, int n_in,
                              void* d_out, int out_size, void* d_ws, size_t ws_size,
                              hipStream_t stream) {
    const float* x = (const float*)d_in[0];
    float* out = (float*)d_out;

    const size_t plane_elems = (size_t)BATCH * CHN * T_LEN;                 // 16.8M
    ushort* zc = (ushort*)d_ws;                                             // 33.55 MB
    ushort* zs = zc + plane_elems;                                          // +33.55 MB
    __half2* partial = (__half2*)((char*)d_ws + 2 * plane_elems * sizeof(ushort)); // +33.55 MB (NKCHUNK=32)

    fft_analytic_kernel<<<BATCH * CHN, 512, 0, stream>>>(x, zc, zs);

    dim3 g2(BATCH, NKCHUNK);
    gram_kernel<<<g2, 512, 0, stream>>>(zc, zs, partial);

    const int n_out = BATCH * CHN * CHN;
    reduce_kernel<<<(n_out + 255) / 256, 256, 0, stream>>>(partial, out);
}